// Round 1
// baseline (855.279 us; speedup 1.0000x reference)
//
#include <hip/hip_runtime.h>
#include <math.h>

#define N_NODES 50000
#define N_EDGES 800000
#define ETOT (N_EDGES + N_NODES)
#define NG 64

__device__ __forceinline__ float leaky02(float a){ return a > 0.f ? a : 0.2f*a; }
__device__ __forceinline__ float eluf(float v){ return v > 0.f ? v : expm1f(v); }

// ---------------- CSR build (by dst), edges = [E real] + [N self-loops] ----------------
__global__ void k_count(const int* __restrict__ ei, unsigned* __restrict__ deg){
  int e = blockIdx.x*256 + threadIdx.x;
  if (e >= ETOT) return;
  int d = (e < N_EDGES) ? ei[N_EDGES + e] : (e - N_EDGES);
  atomicAdd(&deg[d], 1u);
}

__global__ void k_scan(const unsigned* __restrict__ deg, unsigned* __restrict__ off,
                       unsigned* __restrict__ wp){
  __shared__ unsigned ts[1024];
  int t = threadIdx.x;
  const int C = (N_NODES + 1023)/1024;      // 49
  int base = t*C, end = min(base + C, N_NODES);
  unsigned s = 0;
  for (int i = base; i < end; ++i) s += deg[i];
  ts[t] = s; __syncthreads();
  for (int o = 1; o < 1024; o <<= 1){
    unsigned v = (t >= o) ? ts[t-o] : 0u;
    __syncthreads();
    ts[t] += v;
    __syncthreads();
  }
  unsigned acc = ts[t] - s;                  // exclusive prefix
  for (int i = base; i < end; ++i){ off[i] = acc; wp[i] = acc; acc += deg[i]; }
  if (t == 1023) off[N_NODES] = (unsigned)ETOT;
}

__global__ void k_scatter(const int* __restrict__ ei, unsigned* __restrict__ wp,
                          int* __restrict__ csr_src){
  int e = blockIdx.x*256 + threadIdx.x;
  if (e >= ETOT) return;
  int s, d;
  if (e < N_EDGES){ s = ei[e]; d = ei[N_EDGES + e]; } else { s = e - N_EDGES; d = s; }
  unsigned pos = atomicAdd(&wp[d], 1u);
  csr_src[pos] = s;
}

// ---------------- GEMM1: h1 = x @ W1  (128x128), + per-node alpha_src/dst (4 heads) ----
__global__ __launch_bounds__(256) void k_gemm1(const float* __restrict__ x,
    const float* __restrict__ W, const float* __restrict__ attS, const float* __restrict__ attD,
    float* __restrict__ h1, float* __restrict__ asrc, float* __restrict__ adst)
{
  __shared__ float ws[128*128];   // 64 KB
  __shared__ float xs[32*132];    // 16.9 KB, padded stride vs bank conflicts
  int tid = threadIdx.x;
  for (int i = tid; i < 4096; i += 256) ((float4*)ws)[i] = ((const float4*)W)[i];
  int base = blockIdx.x * 32;
  for (int i = tid; i < 1024; i += 256){
    int r = i >> 5, c4 = (i & 31) << 2;
    float4 v = make_float4(0,0,0,0);
    if (base + r < N_NODES) v = *(const float4*)(x + (size_t)(base+r)*128 + c4);
    *(float4*)(xs + r*132 + c4) = v;
  }
  __syncthreads();
  int cg = tid & 31, rq = tid >> 5;          // 4 cols x 4 rows per thread
  int head = cg >> 3;
  float a_s[4], a_d[4];
  #pragma unroll
  for (int j = 0; j < 4; ++j){
    int c = ((cg & 7) << 2) + j;
    a_s[j] = attS[head*32 + c]; a_d[j] = attD[head*32 + c];
  }
  float4 acc[4];
  #pragma unroll
  for (int j = 0; j < 4; ++j) acc[j] = make_float4(0,0,0,0);
  for (int kk = 0; kk < 32; ++kk){
    float4 xv[4];
    #pragma unroll
    for (int j = 0; j < 4; ++j) xv[j] = *(const float4*)(xs + (4*rq + j)*132 + 4*kk);
    #pragma unroll
    for (int t = 0; t < 4; ++t){
      float4 wv = *(const float4*)(ws + (4*kk + t)*128 + 4*cg);
      #pragma unroll
      for (int j = 0; j < 4; ++j){
        float xf = (t==0) ? xv[j].x : (t==1) ? xv[j].y : (t==2) ? xv[j].z : xv[j].w;
        acc[j].x += xf*wv.x; acc[j].y += xf*wv.y; acc[j].z += xf*wv.z; acc[j].w += xf*wv.w;
      }
    }
  }
  #pragma unroll
  for (int j = 0; j < 4; ++j){
    int row = base + 4*rq + j;
    float ps = acc[j].x*a_s[0] + acc[j].y*a_s[1] + acc[j].z*a_s[2] + acc[j].w*a_s[3];
    float pd = acc[j].x*a_d[0] + acc[j].y*a_d[1] + acc[j].z*a_d[2] + acc[j].w*a_d[3];
    #pragma unroll
    for (int m = 1; m <= 4; m <<= 1){ ps += __shfl_xor(ps, m); pd += __shfl_xor(pd, m); }
    if (row < N_NODES){
      *(float4*)(h1 + (size_t)row*128 + 4*cg) = acc[j];
      if ((cg & 7) == 0){ asrc[row*4 + head] = ps; adst[row*4 + head] = pd; }
    }
  }
}

// ---------------- conv1 aggregation: wave per node, H=4, D=32 (128 feat) ---------------
__global__ __launch_bounds__(256) void k_conv1(const unsigned* __restrict__ off,
    const int* __restrict__ csr_src, const float* __restrict__ h1,
    const float* __restrict__ asrc, const float* __restrict__ adst,
    const float* __restrict__ b1, float* __restrict__ helu)
{
  int n = blockIdx.x*4 + (threadIdx.x >> 6);
  int lane = threadIdx.x & 63;
  if (n >= N_NODES) return;
  unsigned s0 = off[n];
  int deg = (int)(off[n+1] - s0);
  float ad0 = adst[n*4+0], ad1 = adst[n*4+1], ad2 = adst[n*4+2], ad3 = adst[n*4+3];
  float m0=-1e30f, m1=-1e30f, m2=-1e30f, m3=-1e30f;
  for (int i = lane; i < deg; i += 64){
    int s = csr_src[s0 + i];
    float4 as = *(const float4*)(asrc + (size_t)s*4);
    m0 = fmaxf(m0, leaky02(as.x + ad0));
    m1 = fmaxf(m1, leaky02(as.y + ad1));
    m2 = fmaxf(m2, leaky02(as.z + ad2));
    m3 = fmaxf(m3, leaky02(as.w + ad3));
  }
  #pragma unroll
  for (int m = 32; m >= 1; m >>= 1){
    m0 = fmaxf(m0, __shfl_xor(m0, m)); m1 = fmaxf(m1, __shfl_xor(m1, m));
    m2 = fmaxf(m2, __shfl_xor(m2, m)); m3 = fmaxf(m3, __shfl_xor(m3, m));
  }
  int h = lane >> 4;                                   // head for dims 2*lane, 2*lane+1
  float mh  = (h==0) ? m0  : (h==1) ? m1  : (h==2) ? m2  : m3;
  float adh = (h==0) ? ad0 : (h==1) ? ad1 : (h==2) ? ad2 : ad3;
  int d0 = lane << 1;
  float den = 0.f, nx = 0.f, ny = 0.f;
  for (int i = 0; i < deg; ++i){
    int s = csr_src[s0 + i];
    float a = leaky02(asrc[s*4 + h] + adh);
    float ev = __expf(a - mh);
    float2 hv = *(const float2*)(h1 + (size_t)s*128 + d0);
    nx += ev*hv.x; ny += ev*hv.y; den += ev;
  }
  float inv = 1.f/(den + 1e-16f);
  float2 o;
  o.x = eluf(nx*inv + b1[d0]);
  o.y = eluf(ny*inv + b1[d0+1]);
  *(float2*)(helu + (size_t)n*128 + d0) = o;
}

// ---------------- GEMM2: h2 = helu @ W2 (128x32), + scalar alphas ----------------------
__global__ __launch_bounds__(256) void k_gemm2(const float* __restrict__ xin,
    const float* __restrict__ W, const float* __restrict__ attS, const float* __restrict__ attD,
    float* __restrict__ h2, float* __restrict__ asrc, float* __restrict__ adst)
{
  __shared__ float ws[128*32];    // 16 KB
  __shared__ float xs[128*132];   // 67.6 KB
  int tid = threadIdx.x;
  for (int i = tid; i < 1024; i += 256) ((float4*)ws)[i] = ((const float4*)W)[i];
  int base = blockIdx.x * 128;
  for (int i = tid; i < 4096; i += 256){
    int r = i >> 5, c4 = (i & 31) << 2;
    float4 v = make_float4(0,0,0,0);
    if (base + r < N_NODES) v = *(const float4*)(xin + (size_t)(base+r)*128 + c4);
    *(float4*)(xs + r*132 + c4) = v;
  }
  __syncthreads();
  int cg = tid & 7, rq = tid >> 3;           // 4 cols x 4 rows per thread; 128 rows/block
  float a_s[4], a_d[4];
  #pragma unroll
  for (int j = 0; j < 4; ++j){ int c = cg*4 + j; a_s[j] = attS[c]; a_d[j] = attD[c]; }
  float4 acc[4];
  #pragma unroll
  for (int j = 0; j < 4; ++j) acc[j] = make_float4(0,0,0,0);
  for (int kk = 0; kk < 32; ++kk){
    float4 xv[4];
    #pragma unroll
    for (int j = 0; j < 4; ++j) xv[j] = *(const float4*)(xs + (4*rq + j)*132 + 4*kk);
    #pragma unroll
    for (int t = 0; t < 4; ++t){
      float4 wv = *(const float4*)(ws + (4*kk + t)*32 + 4*cg);
      #pragma unroll
      for (int j = 0; j < 4; ++j){
        float xf = (t==0) ? xv[j].x : (t==1) ? xv[j].y : (t==2) ? xv[j].z : xv[j].w;
        acc[j].x += xf*wv.x; acc[j].y += xf*wv.y; acc[j].z += xf*wv.z; acc[j].w += xf*wv.w;
      }
    }
  }
  #pragma unroll
  for (int j = 0; j < 4; ++j){
    int row = base + 4*rq + j;
    float ps = acc[j].x*a_s[0] + acc[j].y*a_s[1] + acc[j].z*a_s[2] + acc[j].w*a_s[3];
    float pd = acc[j].x*a_d[0] + acc[j].y*a_d[1] + acc[j].z*a_d[2] + acc[j].w*a_d[3];
    #pragma unroll
    for (int m = 1; m <= 4; m <<= 1){ ps += __shfl_xor(ps, m); pd += __shfl_xor(pd, m); }
    if (row < N_NODES){
      *(float4*)(h2 + (size_t)row*32 + 4*cg) = acc[j];
      if (cg == 0){ asrc[row] = ps; adst[row] = pd; }
    }
  }
}

// ---------------- conv2 aggregation + fused mean-pool scatter (H=1, D=32) --------------
__global__ __launch_bounds__(256) void k_conv2(const unsigned* __restrict__ off,
    const int* __restrict__ csr_src, const float* __restrict__ h2,
    const float* __restrict__ asrc, const float* __restrict__ adst,
    const float* __restrict__ b2, const int* __restrict__ batch,
    float* __restrict__ gsum, float* __restrict__ gcnt)
{
  int n = blockIdx.x*4 + (threadIdx.x >> 6);
  int lane = threadIdx.x & 63;
  if (n >= N_NODES) return;
  unsigned s0 = off[n];
  int deg = (int)(off[n+1] - s0);
  float ad = adst[n];
  float m = -1e30f;
  for (int i = lane; i < deg; i += 64){
    int s = csr_src[s0 + i];
    m = fmaxf(m, leaky02(asrc[s] + ad));
  }
  #pragma unroll
  for (int mm = 32; mm >= 1; mm >>= 1) m = fmaxf(m, __shfl_xor(m, mm));
  int half = lane >> 5, c = lane & 31;     // two edges per iteration
  float den = 0.f, num = 0.f;
  for (int i = 0; i < deg; i += 2){
    int ii = i + half;
    bool act = ii < deg;
    int s = act ? csr_src[s0 + ii] : n;
    float a = leaky02(asrc[s] + ad);
    float ev = act ? __expf(a - m) : 0.f;
    float hv = h2[(size_t)s*32 + c];
    num += ev*hv; den += ev;
  }
  num += __shfl_xor(num, 32); den += __shfl_xor(den, 32);
  int b = batch[n];
  if (lane < 32){
    float val = num/(den + 1e-16f) + b2[c];
    atomicAdd(&gsum[b*32 + c], val);
  } else if (lane == 32){
    atomicAdd(&gcnt[b], 1.0f);
  }
}

// ---------------- final: mean + MLP (64 graphs, 1 block) -------------------------------
__global__ void k_final(const float* __restrict__ gsum, const float* __restrict__ gcnt,
    const float* __restrict__ l1w, const float* __restrict__ l1b,
    const float* __restrict__ l2w, const float* __restrict__ l2b, float* __restrict__ out)
{
  int t = threadIdx.x;
  if (t >= NG) return;
  float cinv = 1.f / fmaxf(gcnt[t], 1.0f);
  float g[32];
  #pragma unroll
  for (int j = 0; j < 32; ++j) g[j] = gsum[t*32 + j] * cinv;
  float o = l2b[0];
  #pragma unroll
  for (int k = 0; k < 16; ++k){
    float hv = l1b[k];
    #pragma unroll
    for (int j = 0; j < 32; ++j) hv += g[j]*l1w[j*16 + k];
    o += eluf(hv) * l2w[k];
  }
  out[t] = o;
}

extern "C" void kernel_launch(void* const* d_in, const int* in_sizes, int n_in,
                              void* d_out, int out_size, void* d_ws, size_t ws_size,
                              hipStream_t stream) {
  const float* x     = (const float*)d_in[0];
  const int*   ei    = (const int*)  d_in[1];
  const int*   batch = (const int*)  d_in[2];
  const float* W1    = (const float*)d_in[3];
  const float* attS1 = (const float*)d_in[4];
  const float* attD1 = (const float*)d_in[5];
  const float* b1    = (const float*)d_in[6];
  const float* W2    = (const float*)d_in[7];
  const float* attS2 = (const float*)d_in[8];
  const float* attD2 = (const float*)d_in[9];
  const float* b2    = (const float*)d_in[10];
  const float* l1w   = (const float*)d_in[11];
  const float* l1b   = (const float*)d_in[12];
  const float* l2w   = (const float*)d_in[13];
  const float* l2b   = (const float*)d_in[14];
  float* out = (float*)d_out;

  char* w = (char*)d_ws;
  auto alloc = [&](size_t elems) -> void* {
    void* p = (void*)w;
    w += ((elems*4 + 255)/256)*256;
    return p;
  };
  unsigned* csr_off = (unsigned*)alloc(N_NODES + 1);
  unsigned* csr_wp  = (unsigned*)alloc(N_NODES);
  unsigned* deg     = (unsigned*)alloc(N_NODES);
  int*      csr_src = (int*)     alloc(ETOT);
  float* h1    = (float*)alloc((size_t)N_NODES*128);
  float* asrc1 = (float*)alloc((size_t)N_NODES*4);
  float* adst1 = (float*)alloc((size_t)N_NODES*4);
  float* helu  = (float*)alloc((size_t)N_NODES*128);
  float* h2    = (float*)alloc((size_t)N_NODES*32);
  float* asrc2 = (float*)alloc(N_NODES);
  float* adst2 = (float*)alloc(N_NODES);
  float* gsum  = (float*)alloc(NG*32);
  float* gcnt  = (float*)alloc(NG);

  hipMemsetAsync(deg,  0, (size_t)N_NODES*4, stream);
  hipMemsetAsync(gsum, 0, (size_t)NG*32*4,   stream);
  hipMemsetAsync(gcnt, 0, (size_t)NG*4,      stream);

  k_count  <<<(ETOT + 255)/256, 256, 0, stream>>>(ei, deg);
  k_scan   <<<1, 1024, 0, stream>>>(deg, csr_off, csr_wp);
  k_scatter<<<(ETOT + 255)/256, 256, 0, stream>>>(ei, csr_wp, csr_src);

  k_gemm1<<<(N_NODES + 31)/32, 256, 0, stream>>>(x, W1, attS1, attD1, h1, asrc1, adst1);
  k_conv1<<<(N_NODES + 3)/4, 256, 0, stream>>>(csr_off, csr_src, h1, asrc1, adst1, b1, helu);
  k_gemm2<<<(N_NODES + 127)/128, 256, 0, stream>>>(helu, W2, attS2, attD2, h2, asrc2, adst2);
  k_conv2<<<(N_NODES + 3)/4, 256, 0, stream>>>(csr_off, csr_src, h2, asrc2, adst2, b2, batch,
                                               gsum, gcnt);
  k_final<<<1, 64, 0, stream>>>(gsum, gcnt, l1w, l1b, l2w, l2b, out);
}

// Round 2
// 443.102 us; speedup vs baseline: 1.9302x; 1.9302x over previous
//
#include <hip/hip_runtime.h>
#include <math.h>

#define N_NODES 50000
#define N_EDGES 800000
#define ETOT (N_EDGES + N_NODES)
#define NG 64

__device__ __forceinline__ float leaky02(float a){ return a > 0.f ? a : 0.2f*a; }
__device__ __forceinline__ float eluf(float v){ return v > 0.f ? v : expm1f(v); }

// ---------------- CSR build (by dst), edges = [E real] + [N self-loops] ----------------
__global__ void k_count(const int* __restrict__ ei, unsigned* __restrict__ deg){
  int e = blockIdx.x*256 + threadIdx.x;
  if (e >= ETOT) return;
  int d = (e < N_EDGES) ? ei[N_EDGES + e] : (e - N_EDGES);
  atomicAdd(&deg[d], 1u);
}

__global__ void k_scan(const unsigned* __restrict__ deg, unsigned* __restrict__ off,
                       unsigned* __restrict__ wp){
  __shared__ unsigned ts[1024];
  int t = threadIdx.x;
  const int C = (N_NODES + 1023)/1024;      // 49
  int base = t*C, end = min(base + C, N_NODES);
  unsigned s = 0;
  for (int i = base; i < end; ++i) s += deg[i];
  ts[t] = s; __syncthreads();
  for (int o = 1; o < 1024; o <<= 1){
    unsigned v = (t >= o) ? ts[t-o] : 0u;
    __syncthreads();
    ts[t] += v;
    __syncthreads();
  }
  unsigned acc = ts[t] - s;                  // exclusive prefix
  for (int i = base; i < end; ++i){ off[i] = acc; wp[i] = acc; acc += deg[i]; }
  if (t == 1023) off[N_NODES] = (unsigned)ETOT;
}

__global__ void k_scatter(const int* __restrict__ ei, unsigned* __restrict__ wp,
                          int* __restrict__ csr_src){
  int e = blockIdx.x*256 + threadIdx.x;
  if (e >= ETOT) return;
  int s, d;
  if (e < N_EDGES){ s = ei[e]; d = ei[N_EDGES + e]; } else { s = e - N_EDGES; d = s; }
  unsigned pos = atomicAdd(&wp[d], 1u);
  csr_src[pos] = s;
}

// ---------------- GEMM1: h1 = x @ W1  (128x128), + per-node alpha_src/dst (4 heads) ----
__global__ __launch_bounds__(256) void k_gemm1(const float* __restrict__ x,
    const float* __restrict__ W, const float* __restrict__ attS, const float* __restrict__ attD,
    float* __restrict__ h1, float* __restrict__ asrc, float* __restrict__ adst)
{
  __shared__ float ws[128*128];   // 64 KB
  __shared__ float xs[32*132];    // 16.9 KB, padded stride vs bank conflicts
  int tid = threadIdx.x;
  for (int i = tid; i < 4096; i += 256) ((float4*)ws)[i] = ((const float4*)W)[i];
  int base = blockIdx.x * 32;
  for (int i = tid; i < 1024; i += 256){
    int r = i >> 5, c4 = (i & 31) << 2;
    float4 v = make_float4(0,0,0,0);
    if (base + r < N_NODES) v = *(const float4*)(x + (size_t)(base+r)*128 + c4);
    *(float4*)(xs + r*132 + c4) = v;
  }
  __syncthreads();
  int cg = tid & 31, rq = tid >> 5;          // 4 cols x 4 rows per thread
  int head = cg >> 3;
  float a_s[4], a_d[4];
  #pragma unroll
  for (int j = 0; j < 4; ++j){
    int c = ((cg & 7) << 2) + j;
    a_s[j] = attS[head*32 + c]; a_d[j] = attD[head*32 + c];
  }
  float4 acc[4];
  #pragma unroll
  for (int j = 0; j < 4; ++j) acc[j] = make_float4(0,0,0,0);
  for (int kk = 0; kk < 32; ++kk){
    float4 xv[4];
    #pragma unroll
    for (int j = 0; j < 4; ++j) xv[j] = *(const float4*)(xs + (4*rq + j)*132 + 4*kk);
    #pragma unroll
    for (int t = 0; t < 4; ++t){
      float4 wv = *(const float4*)(ws + (4*kk + t)*128 + 4*cg);
      #pragma unroll
      for (int j = 0; j < 4; ++j){
        float xf = (t==0) ? xv[j].x : (t==1) ? xv[j].y : (t==2) ? xv[j].z : xv[j].w;
        acc[j].x += xf*wv.x; acc[j].y += xf*wv.y; acc[j].z += xf*wv.z; acc[j].w += xf*wv.w;
      }
    }
  }
  #pragma unroll
  for (int j = 0; j < 4; ++j){
    int row = base + 4*rq + j;
    float ps = acc[j].x*a_s[0] + acc[j].y*a_s[1] + acc[j].z*a_s[2] + acc[j].w*a_s[3];
    float pd = acc[j].x*a_d[0] + acc[j].y*a_d[1] + acc[j].z*a_d[2] + acc[j].w*a_d[3];
    #pragma unroll
    for (int m = 1; m <= 4; m <<= 1){ ps += __shfl_xor(ps, m); pd += __shfl_xor(pd, m); }
    if (row < N_NODES){
      *(float4*)(h1 + (size_t)row*128 + 4*cg) = acc[j];
      if ((cg & 7) == 0){ asrc[row*4 + head] = ps; adst[row*4 + head] = pd; }
    }
  }
}

// ---------------- conv1 aggregation: wave per node, H=4, D=32 (128 feat) ---------------
// Fast path (deg<=64): per-edge scalars computed one-edge-per-lane (parallel gather),
// then feature loop has no dependent scalar loads (shfl broadcast + coalesced row load).
__global__ __launch_bounds__(256) void k_conv1(const unsigned* __restrict__ off,
    const int* __restrict__ csr_src, const float* __restrict__ h1,
    const float* __restrict__ asrc, const float* __restrict__ adst,
    const float* __restrict__ b1, float* __restrict__ helu)
{
  int n = blockIdx.x*4 + (threadIdx.x >> 6);
  int lane = threadIdx.x & 63;
  if (n >= N_NODES) return;
  unsigned s0 = off[n];
  int deg = (int)(off[n+1] - s0);
  float4 ad = *(const float4*)(adst + (size_t)n*4);
  int h = lane >> 4;                                   // head for dims 2*lane, 2*lane+1
  int d0 = lane << 1;
  float den = 0.f, nx = 0.f, ny = 0.f;

  if (deg <= 64){
    int idx = 0;
    float a0=-1e30f, a1=-1e30f, a2=-1e30f, a3=-1e30f;
    if (lane < deg){
      idx = csr_src[s0 + lane];
      float4 as = *(const float4*)(asrc + (size_t)idx*4);
      a0 = leaky02(as.x + ad.x); a1 = leaky02(as.y + ad.y);
      a2 = leaky02(as.z + ad.z); a3 = leaky02(as.w + ad.w);
    }
    float m0=a0, m1=a1, m2=a2, m3=a3;
    #pragma unroll
    for (int m = 32; m >= 1; m >>= 1){
      m0 = fmaxf(m0, __shfl_xor(m0, m)); m1 = fmaxf(m1, __shfl_xor(m1, m));
      m2 = fmaxf(m2, __shfl_xor(m2, m)); m3 = fmaxf(m3, __shfl_xor(m3, m));
    }
    float e0=0.f, e1=0.f, e2=0.f, e3=0.f;
    if (lane < deg){
      e0 = __expf(a0-m0); e1 = __expf(a1-m1); e2 = __expf(a2-m2); e3 = __expf(a3-m3);
    }
    #pragma unroll 4
    for (int i = 0; i < deg; ++i){
      int s = __shfl(idx, i);
      float ei0 = __shfl(e0, i), ei1 = __shfl(e1, i);
      float ei2 = __shfl(e2, i), ei3 = __shfl(e3, i);
      float es = (h==0) ? ei0 : (h==1) ? ei1 : (h==2) ? ei2 : ei3;
      float2 hv = *(const float2*)(h1 + (size_t)s*128 + d0);
      nx += es*hv.x; ny += es*hv.y; den += es;
    }
  } else {
    // rare fallback: serial (deg > 64)
    float m0=-1e30f, m1=-1e30f, m2=-1e30f, m3=-1e30f;
    for (int i = lane; i < deg; i += 64){
      int s = csr_src[s0 + i];
      float4 as = *(const float4*)(asrc + (size_t)s*4);
      m0 = fmaxf(m0, leaky02(as.x + ad.x)); m1 = fmaxf(m1, leaky02(as.y + ad.y));
      m2 = fmaxf(m2, leaky02(as.z + ad.z)); m3 = fmaxf(m3, leaky02(as.w + ad.w));
    }
    #pragma unroll
    for (int m = 32; m >= 1; m >>= 1){
      m0 = fmaxf(m0, __shfl_xor(m0, m)); m1 = fmaxf(m1, __shfl_xor(m1, m));
      m2 = fmaxf(m2, __shfl_xor(m2, m)); m3 = fmaxf(m3, __shfl_xor(m3, m));
    }
    float mh  = (h==0) ? m0 : (h==1) ? m1 : (h==2) ? m2 : m3;
    float adh = (h==0) ? ad.x : (h==1) ? ad.y : (h==2) ? ad.z : ad.w;
    for (int i = 0; i < deg; ++i){
      int s = csr_src[s0 + i];
      float a = leaky02(asrc[s*4 + h] + adh);
      float ev = __expf(a - mh);
      float2 hv = *(const float2*)(h1 + (size_t)s*128 + d0);
      nx += ev*hv.x; ny += ev*hv.y; den += ev;
    }
  }
  float inv = 1.f/(den + 1e-16f);
  float2 o;
  o.x = eluf(nx*inv + b1[d0]);
  o.y = eluf(ny*inv + b1[d0+1]);
  *(float2*)(helu + (size_t)n*128 + d0) = o;
}

// ---------------- GEMM2: h2 = helu @ W2 (128x32), + scalar alphas ----------------------
__global__ __launch_bounds__(256) void k_gemm2(const float* __restrict__ xin,
    const float* __restrict__ W, const float* __restrict__ attS, const float* __restrict__ attD,
    float* __restrict__ h2, float* __restrict__ asrc, float* __restrict__ adst)
{
  __shared__ float ws[128*32];    // 16 KB
  __shared__ float xs[128*132];   // 67.6 KB
  int tid = threadIdx.x;
  for (int i = tid; i < 1024; i += 256) ((float4*)ws)[i] = ((const float4*)W)[i];
  int base = blockIdx.x * 128;
  for (int i = tid; i < 4096; i += 256){
    int r = i >> 5, c4 = (i & 31) << 2;
    float4 v = make_float4(0,0,0,0);
    if (base + r < N_NODES) v = *(const float4*)(xin + (size_t)(base+r)*128 + c4);
    *(float4*)(xs + r*132 + c4) = v;
  }
  __syncthreads();
  int cg = tid & 7, rq = tid >> 3;           // 4 cols x 4 rows per thread; 128 rows/block
  float a_s[4], a_d[4];
  #pragma unroll
  for (int j = 0; j < 4; ++j){ int c = cg*4 + j; a_s[j] = attS[c]; a_d[j] = attD[c]; }
  float4 acc[4];
  #pragma unroll
  for (int j = 0; j < 4; ++j) acc[j] = make_float4(0,0,0,0);
  for (int kk = 0; kk < 32; ++kk){
    float4 xv[4];
    #pragma unroll
    for (int j = 0; j < 4; ++j) xv[j] = *(const float4*)(xs + (4*rq + j)*132 + 4*kk);
    #pragma unroll
    for (int t = 0; t < 4; ++t){
      float4 wv = *(const float4*)(ws + (4*kk + t)*32 + 4*cg);
      #pragma unroll
      for (int j = 0; j < 4; ++j){
        float xf = (t==0) ? xv[j].x : (t==1) ? xv[j].y : (t==2) ? xv[j].z : xv[j].w;
        acc[j].x += xf*wv.x; acc[j].y += xf*wv.y; acc[j].z += xf*wv.z; acc[j].w += xf*wv.w;
      }
    }
  }
  #pragma unroll
  for (int j = 0; j < 4; ++j){
    int row = base + 4*rq + j;
    float ps = acc[j].x*a_s[0] + acc[j].y*a_s[1] + acc[j].z*a_s[2] + acc[j].w*a_s[3];
    float pd = acc[j].x*a_d[0] + acc[j].y*a_d[1] + acc[j].z*a_d[2] + acc[j].w*a_d[3];
    #pragma unroll
    for (int m = 1; m <= 4; m <<= 1){ ps += __shfl_xor(ps, m); pd += __shfl_xor(pd, m); }
    if (row < N_NODES){
      *(float4*)(h2 + (size_t)row*32 + 4*cg) = acc[j];
      if (cg == 0){ asrc[row] = ps; adst[row] = pd; }
    }
  }
}

// ---------------- conv2 aggregation (H=1, D=32): writes per-node output ----------------
__global__ __launch_bounds__(256) void k_conv2(const unsigned* __restrict__ off,
    const int* __restrict__ csr_src, const float* __restrict__ h2,
    const float* __restrict__ asrc, const float* __restrict__ adst,
    const float* __restrict__ b2, float* __restrict__ hout)
{
  int n = blockIdx.x*4 + (threadIdx.x >> 6);
  int lane = threadIdx.x & 63;
  if (n >= N_NODES) return;
  unsigned s0 = off[n];
  int deg = (int)(off[n+1] - s0);
  float ad = adst[n];
  int c = lane & 31, half = lane >> 5;
  float num = 0.f, den = 0.f;

  if (deg <= 64){
    int idx = 0;
    float a = -1e30f;
    if (lane < deg){
      idx = csr_src[s0 + lane];
      a = leaky02(asrc[idx] + ad);
    }
    float m = a;
    #pragma unroll
    for (int mm = 32; mm >= 1; mm >>= 1) m = fmaxf(m, __shfl_xor(m, mm));
    float e = (lane < deg) ? __expf(a - m) : 0.f;
    #pragma unroll 4
    for (int i = 0; i < deg; i += 2){
      int ii = i + half;
      int s  = __shfl(idx, ii);
      float es = __shfl(e, ii);
      int sv = (ii < deg) ? s : 0;
      float hv = h2[(size_t)sv*32 + c];
      num += es*hv; den += es;
    }
  } else {
    float m = -1e30f;
    for (int i = lane; i < deg; i += 64){
      int s = csr_src[s0 + i];
      m = fmaxf(m, leaky02(asrc[s] + ad));
    }
    #pragma unroll
    for (int mm = 32; mm >= 1; mm >>= 1) m = fmaxf(m, __shfl_xor(m, mm));
    for (int i = 0; i < deg; i += 2){
      int ii = i + half;
      bool act = ii < deg;
      int s = act ? csr_src[s0 + ii] : n;
      float a = leaky02(asrc[s] + ad);
      float ev = act ? __expf(a - m) : 0.f;
      float hv = h2[(size_t)s*32 + c];
      num += ev*hv; den += ev;
    }
  }
  num += __shfl_xor(num, 32); den += __shfl_xor(den, 32);
  if (lane < 32) hout[(size_t)n*32 + c] = num/(den + 1e-16f) + b2[c];
}

// ---------------- pool: one block per graph, contiguous segmented mean -----------------
__global__ __launch_bounds__(256) void k_pool(const int* __restrict__ batch,
    const float* __restrict__ hout, float* __restrict__ gmean)
{
  int g = blockIdx.x;
  int a = 0, b = N_NODES;
  while (a < b){ int mid = (a+b)>>1; if (batch[mid] < g) a = mid+1; else b = mid; }
  int lo = a;
  b = N_NODES;
  while (a < b){ int mid = (a+b)>>1; if (batch[mid] < g+1) a = mid+1; else b = mid; }
  int hi = a;
  int c = threadIdx.x & 31, rg = threadIdx.x >> 5;   // 8 row groups
  float s = 0.f;
  for (int r = lo + rg; r < hi; r += 8) s += hout[(size_t)r*32 + c];
  __shared__ float red[8][32];
  red[rg][c] = s;
  __syncthreads();
  if (rg == 0){
    float t = 0.f;
    #pragma unroll
    for (int k = 0; k < 8; ++k) t += red[k][c];
    gmean[g*32 + c] = t / fmaxf((float)(hi - lo), 1.0f);
  }
}

// ---------------- final MLP (64 graphs, 1 block) ---------------------------------------
__global__ void k_final(const float* __restrict__ gmean,
    const float* __restrict__ l1w, const float* __restrict__ l1b,
    const float* __restrict__ l2w, const float* __restrict__ l2b, float* __restrict__ out)
{
  int t = threadIdx.x;
  if (t >= NG) return;
  float g[32];
  #pragma unroll
  for (int j = 0; j < 32; ++j) g[j] = gmean[t*32 + j];
  float o = l2b[0];
  #pragma unroll
  for (int k = 0; k < 16; ++k){
    float hv = l1b[k];
    #pragma unroll
    for (int j = 0; j < 32; ++j) hv += g[j]*l1w[j*16 + k];
    o += eluf(hv) * l2w[k];
  }
  out[t] = o;
}

extern "C" void kernel_launch(void* const* d_in, const int* in_sizes, int n_in,
                              void* d_out, int out_size, void* d_ws, size_t ws_size,
                              hipStream_t stream) {
  const float* x     = (const float*)d_in[0];
  const int*   ei    = (const int*)  d_in[1];
  const int*   batch = (const int*)  d_in[2];
  const float* W1    = (const float*)d_in[3];
  const float* attS1 = (const float*)d_in[4];
  const float* attD1 = (const float*)d_in[5];
  const float* b1    = (const float*)d_in[6];
  const float* W2    = (const float*)d_in[7];
  const float* attS2 = (const float*)d_in[8];
  const float* attD2 = (const float*)d_in[9];
  const float* b2    = (const float*)d_in[10];
  const float* l1w   = (const float*)d_in[11];
  const float* l1b   = (const float*)d_in[12];
  const float* l2w   = (const float*)d_in[13];
  const float* l2b   = (const float*)d_in[14];
  float* out = (float*)d_out;

  char* w = (char*)d_ws;
  auto alloc = [&](size_t elems) -> void* {
    void* p = (void*)w;
    w += ((elems*4 + 255)/256)*256;
    return p;
  };
  unsigned* csr_off = (unsigned*)alloc(N_NODES + 1);
  unsigned* csr_wp  = (unsigned*)alloc(N_NODES);
  unsigned* deg     = (unsigned*)alloc(N_NODES);
  int*      csr_src = (int*)     alloc(ETOT);
  float* h1    = (float*)alloc((size_t)N_NODES*128);
  float* asrc1 = (float*)alloc((size_t)N_NODES*4);
  float* adst1 = (float*)alloc((size_t)N_NODES*4);
  float* helu  = (float*)alloc((size_t)N_NODES*128);
  float* h2    = (float*)alloc((size_t)N_NODES*32);
  float* asrc2 = (float*)alloc(N_NODES);
  float* adst2 = (float*)alloc(N_NODES);
  float* hout  = (float*)alloc((size_t)N_NODES*32);
  float* gmean = (float*)alloc(NG*32);

  hipMemsetAsync(deg, 0, (size_t)N_NODES*4, stream);

  k_count  <<<(ETOT + 255)/256, 256, 0, stream>>>(ei, deg);
  k_scan   <<<1, 1024, 0, stream>>>(deg, csr_off, csr_wp);
  k_scatter<<<(ETOT + 255)/256, 256, 0, stream>>>(ei, csr_wp, csr_src);

  k_gemm1<<<(N_NODES + 31)/32, 256, 0, stream>>>(x, W1, attS1, attD1, h1, asrc1, adst1);
  k_conv1<<<(N_NODES + 3)/4, 256, 0, stream>>>(csr_off, csr_src, h1, asrc1, adst1, b1, helu);
  k_gemm2<<<(N_NODES + 127)/128, 256, 0, stream>>>(helu, W2, attS2, attD2, h2, asrc2, adst2);
  k_conv2<<<(N_NODES + 3)/4, 256, 0, stream>>>(csr_off, csr_src, h2, asrc2, adst2, b2, hout);
  k_pool <<<NG, 256, 0, stream>>>(batch, hout, gmean);
  k_final<<<1, 64, 0, stream>>>(gmean, l1w, l1b, l2w, l2b, out);
}

// Round 3
// 342.106 us; speedup vs baseline: 2.5000x; 1.2952x over previous
//
#include <hip/hip_runtime.h>
#include <math.h>

#define N_NODES 50000
#define N_EDGES 800000
#define ETOT (N_EDGES + N_NODES)
#define NG 64
#define SCAN_NB ((N_NODES + 255)/256)   // 196

__device__ __forceinline__ float leaky02(float a){ return a > 0.f ? a : 0.2f*a; }
__device__ __forceinline__ float eluf(float v){ return v > 0.f ? v : expm1f(v); }

// ---------------- CSR build (by dst), edges = [E real] + [N self-loops] ----------------
__global__ void k_init_deg(unsigned* __restrict__ deg){
  int i = blockIdx.x*256 + threadIdx.x;
  if (i < N_NODES) deg[i] = 1u;            // self-loop
}

__global__ void k_count(const int* __restrict__ ei, unsigned* __restrict__ deg){
  int e = blockIdx.x*256 + threadIdx.x;
  if (e >= N_EDGES) return;
  atomicAdd(&deg[ei[N_EDGES + e]], 1u);
}

// multi-block exclusive scan of deg -> off, wp
__global__ __launch_bounds__(256) void k_scan1(const unsigned* __restrict__ deg,
                                               unsigned* __restrict__ bsum){
  int i = blockIdx.x*256 + threadIdx.x;
  unsigned v = (i < N_NODES) ? deg[i] : 0u;
  #pragma unroll
  for (int o = 32; o >= 1; o >>= 1) v += __shfl_xor(v, o);
  __shared__ unsigned ws[4];
  if ((threadIdx.x & 63) == 0) ws[threadIdx.x >> 6] = v;
  __syncthreads();
  if (threadIdx.x == 0) bsum[blockIdx.x] = ws[0] + ws[1] + ws[2] + ws[3];
}

__global__ __launch_bounds__(256) void k_scan2(const unsigned* __restrict__ bsum,
                                               unsigned* __restrict__ boff){
  __shared__ unsigned ts[256];
  int t = threadIdx.x;
  unsigned v = (t < SCAN_NB) ? bsum[t] : 0u;
  ts[t] = v; __syncthreads();
  #pragma unroll
  for (int o = 1; o < 256; o <<= 1){
    unsigned u = (t >= o) ? ts[t-o] : 0u;
    __syncthreads();
    ts[t] += u;
    __syncthreads();
  }
  if (t < SCAN_NB) boff[t] = ts[t] - v;    // exclusive
}

__global__ __launch_bounds__(256) void k_scan3(const unsigned* __restrict__ deg,
    const unsigned* __restrict__ boff, unsigned* __restrict__ off, unsigned* __restrict__ wp){
  __shared__ unsigned ts[256];
  int t = threadIdx.x;
  int i = blockIdx.x*256 + t;
  unsigned v = (i < N_NODES) ? deg[i] : 0u;
  ts[t] = v; __syncthreads();
  #pragma unroll
  for (int o = 1; o < 256; o <<= 1){
    unsigned u = (t >= o) ? ts[t-o] : 0u;
    __syncthreads();
    ts[t] += u;
    __syncthreads();
  }
  unsigned e = boff[blockIdx.x] + ts[t] - v;
  if (i < N_NODES){ off[i] = e; wp[i] = e; }
  if (i == 0) off[N_NODES] = (unsigned)ETOT;
}

__global__ void k_scatter(const int* __restrict__ ei, unsigned* __restrict__ wp,
                          int* __restrict__ csr_src){
  int e = blockIdx.x*256 + threadIdx.x;
  if (e >= ETOT) return;
  int s, d;
  if (e < N_EDGES){ s = ei[e]; d = ei[N_EDGES + e]; } else { s = e - N_EDGES; d = s; }
  unsigned pos = atomicAdd(&wp[d], 1u);
  csr_src[pos] = s;
}

// ---------------- GEMM1: h1 = x @ W1  (128x128), + per-node alpha_src/dst (4 heads) ----
__global__ __launch_bounds__(256) void k_gemm1(const float* __restrict__ x,
    const float* __restrict__ W, const float* __restrict__ attS, const float* __restrict__ attD,
    float* __restrict__ h1, float* __restrict__ asrc, float* __restrict__ adst)
{
  __shared__ float ws[128*128];   // 64 KB
  __shared__ float xs[32*132];    // 16.9 KB, padded stride vs bank conflicts
  int tid = threadIdx.x;
  for (int i = tid; i < 4096; i += 256) ((float4*)ws)[i] = ((const float4*)W)[i];
  int base = blockIdx.x * 32;
  for (int i = tid; i < 1024; i += 256){
    int r = i >> 5, c4 = (i & 31) << 2;
    float4 v = make_float4(0,0,0,0);
    if (base + r < N_NODES) v = *(const float4*)(x + (size_t)(base+r)*128 + c4);
    *(float4*)(xs + r*132 + c4) = v;
  }
  __syncthreads();
  int cg = tid & 31, rq = tid >> 5;          // 4 cols x 4 rows per thread
  int head = cg >> 3;
  float a_s[4], a_d[4];
  #pragma unroll
  for (int j = 0; j < 4; ++j){
    int c = ((cg & 7) << 2) + j;
    a_s[j] = attS[head*32 + c]; a_d[j] = attD[head*32 + c];
  }
  float4 acc[4];
  #pragma unroll
  for (int j = 0; j < 4; ++j) acc[j] = make_float4(0,0,0,0);
  for (int kk = 0; kk < 32; ++kk){
    float4 xv[4];
    #pragma unroll
    for (int j = 0; j < 4; ++j) xv[j] = *(const float4*)(xs + (4*rq + j)*132 + 4*kk);
    #pragma unroll
    for (int t = 0; t < 4; ++t){
      float4 wv = *(const float4*)(ws + (4*kk + t)*128 + 4*cg);
      #pragma unroll
      for (int j = 0; j < 4; ++j){
        float xf = (t==0) ? xv[j].x : (t==1) ? xv[j].y : (t==2) ? xv[j].z : xv[j].w;
        acc[j].x += xf*wv.x; acc[j].y += xf*wv.y; acc[j].z += xf*wv.z; acc[j].w += xf*wv.w;
      }
    }
  }
  #pragma unroll
  for (int j = 0; j < 4; ++j){
    int row = base + 4*rq + j;
    float ps = acc[j].x*a_s[0] + acc[j].y*a_s[1] + acc[j].z*a_s[2] + acc[j].w*a_s[3];
    float pd = acc[j].x*a_d[0] + acc[j].y*a_d[1] + acc[j].z*a_d[2] + acc[j].w*a_d[3];
    #pragma unroll
    for (int m = 1; m <= 4; m <<= 1){ ps += __shfl_xor(ps, m); pd += __shfl_xor(pd, m); }
    if (row < N_NODES){
      *(float4*)(h1 + (size_t)row*128 + 4*cg) = acc[j];
      if ((cg & 7) == 0){ asrc[row*4 + head] = ps; adst[row*4 + head] = pd; }
    }
  }
}

// ---------------- conv1 aggregation: wave per node, H=4, D=32 (128 feat) ---------------
__global__ __launch_bounds__(256) void k_conv1(const unsigned* __restrict__ off,
    const int* __restrict__ csr_src, const float* __restrict__ h1,
    const float* __restrict__ asrc, const float* __restrict__ adst,
    const float* __restrict__ b1, float* __restrict__ helu)
{
  int n = blockIdx.x*4 + (threadIdx.x >> 6);
  int lane = threadIdx.x & 63;
  if (n >= N_NODES) return;
  unsigned s0 = off[n];
  int deg = (int)(off[n+1] - s0);
  float4 ad = *(const float4*)(adst + (size_t)n*4);
  int h = lane >> 4;                                   // head for dims 2*lane, 2*lane+1
  int d0 = lane << 1;
  float den = 0.f, nx = 0.f, ny = 0.f;

  if (deg <= 64){
    int idx = 0;
    float a0=-1e30f, a1=-1e30f, a2=-1e30f, a3=-1e30f;
    if (lane < deg){
      idx = csr_src[s0 + lane];
      float4 as = *(const float4*)(asrc + (size_t)idx*4);
      a0 = leaky02(as.x + ad.x); a1 = leaky02(as.y + ad.y);
      a2 = leaky02(as.z + ad.z); a3 = leaky02(as.w + ad.w);
    }
    float m0=a0, m1=a1, m2=a2, m3=a3;
    #pragma unroll
    for (int m = 32; m >= 1; m >>= 1){
      m0 = fmaxf(m0, __shfl_xor(m0, m)); m1 = fmaxf(m1, __shfl_xor(m1, m));
      m2 = fmaxf(m2, __shfl_xor(m2, m)); m3 = fmaxf(m3, __shfl_xor(m3, m));
    }
    float e0=0.f, e1=0.f, e2=0.f, e3=0.f;
    if (lane < deg){
      e0 = __expf(a0-m0); e1 = __expf(a1-m1); e2 = __expf(a2-m2); e3 = __expf(a3-m3);
    }
    #pragma unroll 4
    for (int i = 0; i < deg; ++i){
      int s = __shfl(idx, i);
      float ei0 = __shfl(e0, i), ei1 = __shfl(e1, i);
      float ei2 = __shfl(e2, i), ei3 = __shfl(e3, i);
      float es = (h==0) ? ei0 : (h==1) ? ei1 : (h==2) ? ei2 : ei3;
      float2 hv = *(const float2*)(h1 + (size_t)s*128 + d0);
      nx += es*hv.x; ny += es*hv.y; den += es;
    }
  } else {
    // rare fallback: serial (deg > 64)
    float m0=-1e30f, m1=-1e30f, m2=-1e30f, m3=-1e30f;
    for (int i = lane; i < deg; i += 64){
      int s = csr_src[s0 + i];
      float4 as = *(const float4*)(asrc + (size_t)s*4);
      m0 = fmaxf(m0, leaky02(as.x + ad.x)); m1 = fmaxf(m1, leaky02(as.y + ad.y));
      m2 = fmaxf(m2, leaky02(as.z + ad.z)); m3 = fmaxf(m3, leaky02(as.w + ad.w));
    }
    #pragma unroll
    for (int m = 32; m >= 1; m >>= 1){
      m0 = fmaxf(m0, __shfl_xor(m0, m)); m1 = fmaxf(m1, __shfl_xor(m1, m));
      m2 = fmaxf(m2, __shfl_xor(m2, m)); m3 = fmaxf(m3, __shfl_xor(m3, m));
    }
    float mh  = (h==0) ? m0 : (h==1) ? m1 : (h==2) ? m2 : m3;
    float adh = (h==0) ? ad.x : (h==1) ? ad.y : (h==2) ? ad.z : ad.w;
    for (int i = 0; i < deg; ++i){
      int s = csr_src[s0 + i];
      float a = leaky02(asrc[s*4 + h] + adh);
      float ev = __expf(a - mh);
      float2 hv = *(const float2*)(h1 + (size_t)s*128 + d0);
      nx += ev*hv.x; ny += ev*hv.y; den += ev;
    }
  }
  float inv = 1.f/(den + 1e-16f);
  float2 o;
  o.x = eluf(nx*inv + b1[d0]);
  o.y = eluf(ny*inv + b1[d0+1]);
  *(float2*)(helu + (size_t)n*128 + d0) = o;
}

// ---------------- GEMM2: h2 = helu @ W2 (128x32), + scalar alphas ----------------------
__global__ __launch_bounds__(256) void k_gemm2(const float* __restrict__ xin,
    const float* __restrict__ W, const float* __restrict__ attS, const float* __restrict__ attD,
    float* __restrict__ h2, float* __restrict__ asrc, float* __restrict__ adst)
{
  __shared__ float ws[128*32];    // 16 KB
  __shared__ float xs[128*132];   // 67.6 KB
  int tid = threadIdx.x;
  for (int i = tid; i < 1024; i += 256) ((float4*)ws)[i] = ((const float4*)W)[i];
  int base = blockIdx.x * 128;
  for (int i = tid; i < 4096; i += 256){
    int r = i >> 5, c4 = (i & 31) << 2;
    float4 v = make_float4(0,0,0,0);
    if (base + r < N_NODES) v = *(const float4*)(xin + (size_t)(base+r)*128 + c4);
    *(float4*)(xs + r*132 + c4) = v;
  }
  __syncthreads();
  int cg = tid & 7, rq = tid >> 3;           // 4 cols x 4 rows per thread; 128 rows/block
  float a_s[4], a_d[4];
  #pragma unroll
  for (int j = 0; j < 4; ++j){ int c = cg*4 + j; a_s[j] = attS[c]; a_d[j] = attD[c]; }
  float4 acc[4];
  #pragma unroll
  for (int j = 0; j < 4; ++j) acc[j] = make_float4(0,0,0,0);
  for (int kk = 0; kk < 32; ++kk){
    float4 xv[4];
    #pragma unroll
    for (int j = 0; j < 4; ++j) xv[j] = *(const float4*)(xs + (4*rq + j)*132 + 4*kk);
    #pragma unroll
    for (int t = 0; t < 4; ++t){
      float4 wv = *(const float4*)(ws + (4*kk + t)*32 + 4*cg);
      #pragma unroll
      for (int j = 0; j < 4; ++j){
        float xf = (t==0) ? xv[j].x : (t==1) ? xv[j].y : (t==2) ? xv[j].z : xv[j].w;
        acc[j].x += xf*wv.x; acc[j].y += xf*wv.y; acc[j].z += xf*wv.z; acc[j].w += xf*wv.w;
      }
    }
  }
  #pragma unroll
  for (int j = 0; j < 4; ++j){
    int row = base + 4*rq + j;
    float ps = acc[j].x*a_s[0] + acc[j].y*a_s[1] + acc[j].z*a_s[2] + acc[j].w*a_s[3];
    float pd = acc[j].x*a_d[0] + acc[j].y*a_d[1] + acc[j].z*a_d[2] + acc[j].w*a_d[3];
    #pragma unroll
    for (int m = 1; m <= 4; m <<= 1){ ps += __shfl_xor(ps, m); pd += __shfl_xor(pd, m); }
    if (row < N_NODES){
      *(float4*)(h2 + (size_t)row*32 + 4*cg) = acc[j];
      if (cg == 0){ asrc[row] = ps; adst[row] = pd; }
    }
  }
}

// ---------------- conv2 aggregation (H=1, D=32): writes per-node output ----------------
__global__ __launch_bounds__(256) void k_conv2(const unsigned* __restrict__ off,
    const int* __restrict__ csr_src, const float* __restrict__ h2,
    const float* __restrict__ asrc, const float* __restrict__ adst,
    const float* __restrict__ b2, float* __restrict__ hout)
{
  int n = blockIdx.x*4 + (threadIdx.x >> 6);
  int lane = threadIdx.x & 63;
  if (n >= N_NODES) return;
  unsigned s0 = off[n];
  int deg = (int)(off[n+1] - s0);
  float ad = adst[n];
  int c = lane & 31, half = lane >> 5;
  float num = 0.f, den = 0.f;

  if (deg <= 64){
    int idx = 0;
    float a = -1e30f;
    if (lane < deg){
      idx = csr_src[s0 + lane];
      a = leaky02(asrc[idx] + ad);
    }
    float m = a;
    #pragma unroll
    for (int mm = 32; mm >= 1; mm >>= 1) m = fmaxf(m, __shfl_xor(m, mm));
    float e = (lane < deg) ? __expf(a - m) : 0.f;
    #pragma unroll 4
    for (int i = 0; i < deg; i += 2){
      int ii = i + half;
      int s  = __shfl(idx, ii);
      float es = __shfl(e, ii);
      int sv = (ii < deg) ? s : 0;
      float hv = h2[(size_t)sv*32 + c];
      num += es*hv; den += es;
    }
  } else {
    float m = -1e30f;
    for (int i = lane; i < deg; i += 64){
      int s = csr_src[s0 + i];
      m = fmaxf(m, leaky02(asrc[s] + ad));
    }
    #pragma unroll
    for (int mm = 32; mm >= 1; mm >>= 1) m = fmaxf(m, __shfl_xor(m, mm));
    for (int i = 0; i < deg; i += 2){
      int ii = i + half;
      bool act = ii < deg;
      int s = act ? csr_src[s0 + ii] : n;
      float a = leaky02(asrc[s] + ad);
      float ev = act ? __expf(a - m) : 0.f;
      float hv = h2[(size_t)s*32 + c];
      num += ev*hv; den += ev;
    }
  }
  num += __shfl_xor(num, 32); den += __shfl_xor(den, 32);
  if (lane < 32) hout[(size_t)n*32 + c] = num/(den + 1e-16f) + b2[c];
}

// ---------------- pool: one block per graph, contiguous segmented mean -----------------
__global__ __launch_bounds__(256) void k_pool(const int* __restrict__ batch,
    const float* __restrict__ hout, float* __restrict__ gmean)
{
  int g = blockIdx.x;
  int a = 0, b = N_NODES;
  while (a < b){ int mid = (a+b)>>1; if (batch[mid] < g) a = mid+1; else b = mid; }
  int lo = a;
  b = N_NODES;
  while (a < b){ int mid = (a+b)>>1; if (batch[mid] < g+1) a = mid+1; else b = mid; }
  int hi = a;
  int c = threadIdx.x & 31, rg = threadIdx.x >> 5;   // 8 row groups
  float s = 0.f;
  for (int r = lo + rg; r < hi; r += 8) s += hout[(size_t)r*32 + c];
  __shared__ float red[8][32];
  red[rg][c] = s;
  __syncthreads();
  if (rg == 0){
    float t = 0.f;
    #pragma unroll
    for (int k = 0; k < 8; ++k) t += red[k][c];
    gmean[g*32 + c] = t / fmaxf((float)(hi - lo), 1.0f);
  }
}

// ---------------- final MLP (64 graphs, 1 block) ---------------------------------------
__global__ void k_final(const float* __restrict__ gmean,
    const float* __restrict__ l1w, const float* __restrict__ l1b,
    const float* __restrict__ l2w, const float* __restrict__ l2b, float* __restrict__ out)
{
  int t = threadIdx.x;
  if (t >= NG) return;
  float g[32];
  #pragma unroll
  for (int j = 0; j < 32; ++j) g[j] = gmean[t*32 + j];
  float o = l2b[0];
  #pragma unroll
  for (int k = 0; k < 16; ++k){
    float hv = l1b[k];
    #pragma unroll
    for (int j = 0; j < 32; ++j) hv += g[j]*l1w[j*16 + k];
    o += eluf(hv) * l2w[k];
  }
  out[t] = o;
}

extern "C" void kernel_launch(void* const* d_in, const int* in_sizes, int n_in,
                              void* d_out, int out_size, void* d_ws, size_t ws_size,
                              hipStream_t stream) {
  const float* x     = (const float*)d_in[0];
  const int*   ei    = (const int*)  d_in[1];
  const int*   batch = (const int*)  d_in[2];
  const float* W1    = (const float*)d_in[3];
  const float* attS1 = (const float*)d_in[4];
  const float* attD1 = (const float*)d_in[5];
  const float* b1    = (const float*)d_in[6];
  const float* W2    = (const float*)d_in[7];
  const float* attS2 = (const float*)d_in[8];
  const float* attD2 = (const float*)d_in[9];
  const float* b2    = (const float*)d_in[10];
  const float* l1w   = (const float*)d_in[11];
  const float* l1b   = (const float*)d_in[12];
  const float* l2w   = (const float*)d_in[13];
  const float* l2b   = (const float*)d_in[14];
  float* out = (float*)d_out;

  char* w = (char*)d_ws;
  auto alloc = [&](size_t elems) -> void* {
    void* p = (void*)w;
    w += ((elems*4 + 255)/256)*256;
    return p;
  };
  unsigned* csr_off = (unsigned*)alloc(N_NODES + 1);
  unsigned* csr_wp  = (unsigned*)alloc(N_NODES);
  unsigned* deg     = (unsigned*)alloc(N_NODES);
  unsigned* bsum    = (unsigned*)alloc(SCAN_NB);
  unsigned* boff    = (unsigned*)alloc(SCAN_NB);
  int*      csr_src = (int*)     alloc(ETOT);
  float* h1    = (float*)alloc((size_t)N_NODES*128);
  float* asrc1 = (float*)alloc((size_t)N_NODES*4);
  float* adst1 = (float*)alloc((size_t)N_NODES*4);
  float* helu  = (float*)alloc((size_t)N_NODES*128);
  float* h2    = (float*)alloc((size_t)N_NODES*32);
  float* asrc2 = (float*)alloc(N_NODES);
  float* adst2 = (float*)alloc(N_NODES);
  float* hout  = (float*)alloc((size_t)N_NODES*32);
  float* gmean = (float*)alloc(NG*32);

  k_init_deg<<<SCAN_NB, 256, 0, stream>>>(deg);
  k_count   <<<(N_EDGES + 255)/256, 256, 0, stream>>>(ei, deg);
  k_scan1   <<<SCAN_NB, 256, 0, stream>>>(deg, bsum);
  k_scan2   <<<1, 256, 0, stream>>>(bsum, boff);
  k_scan3   <<<SCAN_NB, 256, 0, stream>>>(deg, boff, csr_off, csr_wp);
  k_scatter <<<(ETOT + 255)/256, 256, 0, stream>>>(ei, csr_wp, csr_src);

  k_gemm1<<<(N_NODES + 31)/32, 256, 0, stream>>>(x, W1, attS1, attD1, h1, asrc1, adst1);
  k_conv1<<<(N_NODES + 3)/4, 256, 0, stream>>>(csr_off, csr_src, h1, asrc1, adst1, b1, helu);
  k_gemm2<<<(N_NODES + 127)/128, 256, 0, stream>>>(helu, W2, attS2, attD2, h2, asrc2, adst2);
  k_conv2<<<(N_NODES + 3)/4, 256, 0, stream>>>(csr_off, csr_src, h2, asrc2, adst2, b2, hout);
  k_pool <<<NG, 256, 0, stream>>>(batch, hout, gmean);
  k_final<<<1, 64, 0, stream>>>(gmean, l1w, l1b, l2w, l2b, out);
}

// Round 4
// 313.335 us; speedup vs baseline: 2.7296x; 1.0918x over previous
//
#include <hip/hip_runtime.h>
#include <math.h>

#define N_NODES 50000
#define N_EDGES 800000
#define ETOT (N_EDGES + N_NODES)
#define NG 64
#define SCAN_NB ((N_NODES + 255)/256)   // 196

__device__ __forceinline__ float leaky02(float a){ return a > 0.f ? a : 0.2f*a; }
__device__ __forceinline__ float eluf(float v){ return v > 0.f ? v : expm1f(v); }

// ---------------- CSR build (by dst), edges = [E real] + [N self-loops] ----------------
__global__ void k_init_deg(unsigned* __restrict__ deg){
  int i = blockIdx.x*256 + threadIdx.x;
  if (i < N_NODES) deg[i] = 1u;            // self-loop
}

__global__ void k_count(const int* __restrict__ ei, unsigned* __restrict__ deg){
  int e = blockIdx.x*256 + threadIdx.x;
  if (e >= N_EDGES) return;
  atomicAdd(&deg[ei[N_EDGES + e]], 1u);
}

// multi-block exclusive scan of deg -> off, wp
__global__ __launch_bounds__(256) void k_scan1(const unsigned* __restrict__ deg,
                                               unsigned* __restrict__ bsum){
  int i = blockIdx.x*256 + threadIdx.x;
  unsigned v = (i < N_NODES) ? deg[i] : 0u;
  #pragma unroll
  for (int o = 32; o >= 1; o >>= 1) v += __shfl_xor(v, o);
  __shared__ unsigned ws[4];
  if ((threadIdx.x & 63) == 0) ws[threadIdx.x >> 6] = v;
  __syncthreads();
  if (threadIdx.x == 0) bsum[blockIdx.x] = ws[0] + ws[1] + ws[2] + ws[3];
}

__global__ __launch_bounds__(256) void k_scan2(const unsigned* __restrict__ bsum,
                                               unsigned* __restrict__ boff){
  __shared__ unsigned ts[256];
  int t = threadIdx.x;
  unsigned v = (t < SCAN_NB) ? bsum[t] : 0u;
  ts[t] = v; __syncthreads();
  for (int o = 1; o < 256; o <<= 1){
    unsigned u = (t >= o) ? ts[t-o] : 0u;
    __syncthreads();
    ts[t] += u;
    __syncthreads();
  }
  if (t < SCAN_NB) boff[t] = ts[t] - v;    // exclusive
}

__global__ __launch_bounds__(256) void k_scan3(const unsigned* __restrict__ deg,
    const unsigned* __restrict__ boff, unsigned* __restrict__ off, unsigned* __restrict__ wp){
  __shared__ unsigned ts[256];
  int t = threadIdx.x;
  int i = blockIdx.x*256 + t;
  unsigned v = (i < N_NODES) ? deg[i] : 0u;
  ts[t] = v; __syncthreads();
  for (int o = 1; o < 256; o <<= 1){
    unsigned u = (t >= o) ? ts[t-o] : 0u;
    __syncthreads();
    ts[t] += u;
    __syncthreads();
  }
  unsigned e = boff[blockIdx.x] + ts[t] - v;
  if (i < N_NODES){ off[i] = e; wp[i] = e; }
  if (i == 0) off[N_NODES] = (unsigned)ETOT;
}

__global__ void k_scatter(const int* __restrict__ ei, unsigned* __restrict__ wp,
                          int* __restrict__ csr_src){
  int e = blockIdx.x*256 + threadIdx.x;
  if (e >= ETOT) return;
  int s, d;
  if (e < N_EDGES){ s = ei[e]; d = ei[N_EDGES + e]; } else { s = e - N_EDGES; d = s; }
  unsigned pos = atomicAdd(&wp[d], 1u);
  csr_src[pos] = s;
}

// ---------------- GEMM1: h1 = x @ W1  (128x128), + per-node alpha_src/dst (4 heads) ----
__global__ __launch_bounds__(256) void k_gemm1(const float* __restrict__ x,
    const float* __restrict__ W, const float* __restrict__ attS, const float* __restrict__ attD,
    float* __restrict__ h1, float* __restrict__ asrc, float* __restrict__ adst)
{
  __shared__ float ws[128*128];   // 64 KB
  __shared__ float xs[32*132];    // 16.9 KB
  int tid = threadIdx.x;
  for (int i = tid; i < 4096; i += 256) ((float4*)ws)[i] = ((const float4*)W)[i];
  int base = blockIdx.x * 32;
  for (int i = tid; i < 1024; i += 256){
    int r = i >> 5, c4 = (i & 31) << 2;
    float4 v = make_float4(0,0,0,0);
    if (base + r < N_NODES) v = *(const float4*)(x + (size_t)(base+r)*128 + c4);
    *(float4*)(xs + r*132 + c4) = v;
  }
  __syncthreads();
  int cg = tid & 31, rq = tid >> 5;          // 4 cols x 4 rows per thread
  int head = cg >> 3;
  float a_s[4], a_d[4];
  #pragma unroll
  for (int j = 0; j < 4; ++j){
    int c = ((cg & 7) << 2) + j;
    a_s[j] = attS[head*32 + c]; a_d[j] = attD[head*32 + c];
  }
  float4 acc[4];
  #pragma unroll
  for (int j = 0; j < 4; ++j) acc[j] = make_float4(0,0,0,0);
  for (int kk = 0; kk < 32; ++kk){
    float4 xv[4];
    #pragma unroll
    for (int j = 0; j < 4; ++j) xv[j] = *(const float4*)(xs + (4*rq + j)*132 + 4*kk);
    #pragma unroll
    for (int t = 0; t < 4; ++t){
      float4 wv = *(const float4*)(ws + (4*kk + t)*128 + 4*cg);
      #pragma unroll
      for (int j = 0; j < 4; ++j){
        float xf = (t==0) ? xv[j].x : (t==1) ? xv[j].y : (t==2) ? xv[j].z : xv[j].w;
        acc[j].x += xf*wv.x; acc[j].y += xf*wv.y; acc[j].z += xf*wv.z; acc[j].w += xf*wv.w;
      }
    }
  }
  #pragma unroll
  for (int j = 0; j < 4; ++j){
    int row = base + 4*rq + j;
    float ps = acc[j].x*a_s[0] + acc[j].y*a_s[1] + acc[j].z*a_s[2] + acc[j].w*a_s[3];
    float pd = acc[j].x*a_d[0] + acc[j].y*a_d[1] + acc[j].z*a_d[2] + acc[j].w*a_d[3];
    #pragma unroll
    for (int m = 1; m <= 4; m <<= 1){ ps += __shfl_xor(ps, m); pd += __shfl_xor(pd, m); }
    if (row < N_NODES){
      *(float4*)(h1 + (size_t)row*128 + 4*cg) = acc[j];
      if ((cg & 7) == 0){ asrc[row*4 + head] = ps; adst[row*4 + head] = pd; }
    }
  }
}

// ---------------- conv1: wave/node; 2 edges per iter, float4 row loads, LDS-staged e ---
__global__ __launch_bounds__(256) void k_conv1(const unsigned* __restrict__ off,
    const int* __restrict__ csr_src, const float* __restrict__ h1,
    const float* __restrict__ asrc, const float* __restrict__ adst,
    const float* __restrict__ b1, float* __restrict__ helu)
{
  __shared__ float4 eh4[4][68];   // [wave][edge] -> e for heads 0..3
  __shared__ int    idxs[4][68];
  int w    = threadIdx.x >> 6;
  int lane = threadIdx.x & 63;
  int n = blockIdx.x*4 + w;
  if (n >= N_NODES) return;
  unsigned s0 = off[n];
  int deg = (int)(off[n+1] - s0);
  float4 ad = *(const float4*)(adst + (size_t)n*4);
  int cl = lane & 31;             // feature group: floats 4*cl..4*cl+3
  int h  = cl >> 3;               // head of this feature group
  float4 acc = make_float4(0,0,0,0);
  float den = 0.f;

  if (deg <= 64){
    int idx = 0;
    float a0=-1e30f, a1=-1e30f, a2=-1e30f, a3=-1e30f;
    if (lane < deg){
      idx = csr_src[s0 + lane];
      float4 as = *(const float4*)(asrc + (size_t)idx*4);
      a0 = leaky02(as.x + ad.x); a1 = leaky02(as.y + ad.y);
      a2 = leaky02(as.z + ad.z); a3 = leaky02(as.w + ad.w);
    }
    float m0=a0, m1=a1, m2=a2, m3=a3;
    #pragma unroll
    for (int m = 32; m >= 1; m >>= 1){
      m0 = fmaxf(m0, __shfl_xor(m0, m)); m1 = fmaxf(m1, __shfl_xor(m1, m));
      m2 = fmaxf(m2, __shfl_xor(m2, m)); m3 = fmaxf(m3, __shfl_xor(m3, m));
    }
    float4 ev = make_float4(0,0,0,0);
    if (lane < deg){
      ev.x = __expf(a0-m0); ev.y = __expf(a1-m1);
      ev.z = __expf(a2-m2); ev.w = __expf(a3-m3);
    }
    eh4[w][lane] = ev;
    idxs[w][lane] = idx;
    if (lane < 4){ eh4[w][64+lane] = make_float4(0,0,0,0); idxs[w][64+lane] = 0; }
    __builtin_amdgcn_wave_barrier();   // wave-coherent LDS: in-order DS, no s_barrier
    int half = lane >> 5;
    #pragma unroll 4
    for (int i = 0; i < deg; i += 2){
      int ii = i + half;
      float es = ((const float*)&eh4[w][ii])[h];
      int s = idxs[w][ii];
      float4 hv = *(const float4*)(h1 + (size_t)s*128 + 4*cl);
      acc.x += es*hv.x; acc.y += es*hv.y; acc.z += es*hv.z; acc.w += es*hv.w;
      den += es;
    }
    acc.x += __shfl_xor(acc.x, 32); acc.y += __shfl_xor(acc.y, 32);
    acc.z += __shfl_xor(acc.z, 32); acc.w += __shfl_xor(acc.w, 32);
    den   += __shfl_xor(den, 32);
  } else {
    // rare fallback: serial (deg > 64)
    float m0=-1e30f, m1=-1e30f, m2=-1e30f, m3=-1e30f;
    for (int i = lane; i < deg; i += 64){
      int s = csr_src[s0 + i];
      float4 as = *(const float4*)(asrc + (size_t)s*4);
      m0 = fmaxf(m0, leaky02(as.x + ad.x)); m1 = fmaxf(m1, leaky02(as.y + ad.y));
      m2 = fmaxf(m2, leaky02(as.z + ad.z)); m3 = fmaxf(m3, leaky02(as.w + ad.w));
    }
    #pragma unroll
    for (int m = 32; m >= 1; m >>= 1){
      m0 = fmaxf(m0, __shfl_xor(m0, m)); m1 = fmaxf(m1, __shfl_xor(m1, m));
      m2 = fmaxf(m2, __shfl_xor(m2, m)); m3 = fmaxf(m3, __shfl_xor(m3, m));
    }
    float mh  = (h==0) ? m0 : (h==1) ? m1 : (h==2) ? m2 : m3;
    float adh = (h==0) ? ad.x : (h==1) ? ad.y : (h==2) ? ad.z : ad.w;
    for (int i = 0; i < deg; ++i){
      int s = csr_src[s0 + i];
      float a = leaky02(asrc[s*4 + h] + adh);
      float ev = __expf(a - mh);
      float4 hv = *(const float4*)(h1 + (size_t)s*128 + 4*cl);
      acc.x += ev*hv.x; acc.y += ev*hv.y; acc.z += ev*hv.z; acc.w += ev*hv.w;
      den += ev;
    }
    // halves computed identical full sums? No: serial loop covered all edges per lane.
    // Each lane already has the full sum; no combine needed.
  }
  if (lane < 32){
    float inv = 1.f/(den + 1e-16f);
    float4 bv = ((const float4*)b1)[cl];
    float4 o;
    o.x = eluf(acc.x*inv + bv.x); o.y = eluf(acc.y*inv + bv.y);
    o.z = eluf(acc.z*inv + bv.z); o.w = eluf(acc.w*inv + bv.w);
    *(float4*)(helu + (size_t)n*128 + 4*cl) = o;
  }
}

// ---------------- GEMM2: h2 = helu @ W2 (128x32), + scalar alphas ----------------------
__global__ __launch_bounds__(256) void k_gemm2(const float* __restrict__ xin,
    const float* __restrict__ W, const float* __restrict__ attS, const float* __restrict__ attD,
    float* __restrict__ h2, float* __restrict__ asrc, float* __restrict__ adst)
{
  __shared__ float ws[128*32];    // 16 KB
  __shared__ float xs[128*132];   // 67.6 KB
  int tid = threadIdx.x;
  for (int i = tid; i < 1024; i += 256) ((float4*)ws)[i] = ((const float4*)W)[i];
  int base = blockIdx.x * 128;
  for (int i = tid; i < 4096; i += 256){
    int r = i >> 5, c4 = (i & 31) << 2;
    float4 v = make_float4(0,0,0,0);
    if (base + r < N_NODES) v = *(const float4*)(xin + (size_t)(base+r)*128 + c4);
    *(float4*)(xs + r*132 + c4) = v;
  }
  __syncthreads();
  int cg = tid & 7, rq = tid >> 3;           // 4 cols x 4 rows per thread
  float a_s[4], a_d[4];
  #pragma unroll
  for (int j = 0; j < 4; ++j){ int c = cg*4 + j; a_s[j] = attS[c]; a_d[j] = attD[c]; }
  float4 acc[4];
  #pragma unroll
  for (int j = 0; j < 4; ++j) acc[j] = make_float4(0,0,0,0);
  for (int kk = 0; kk < 32; ++kk){
    float4 xv[4];
    #pragma unroll
    for (int j = 0; j < 4; ++j) xv[j] = *(const float4*)(xs + (4*rq + j)*132 + 4*kk);
    #pragma unroll
    for (int t = 0; t < 4; ++t){
      float4 wv = *(const float4*)(ws + (4*kk + t)*32 + 4*cg);
      #pragma unroll
      for (int j = 0; j < 4; ++j){
        float xf = (t==0) ? xv[j].x : (t==1) ? xv[j].y : (t==2) ? xv[j].z : xv[j].w;
        acc[j].x += xf*wv.x; acc[j].y += xf*wv.y; acc[j].z += xf*wv.z; acc[j].w += xf*wv.w;
      }
    }
  }
  #pragma unroll
  for (int j = 0; j < 4; ++j){
    int row = base + 4*rq + j;
    float ps = acc[j].x*a_s[0] + acc[j].y*a_s[1] + acc[j].z*a_s[2] + acc[j].w*a_s[3];
    float pd = acc[j].x*a_d[0] + acc[j].y*a_d[1] + acc[j].z*a_d[2] + acc[j].w*a_d[3];
    #pragma unroll
    for (int m = 1; m <= 4; m <<= 1){ ps += __shfl_xor(ps, m); pd += __shfl_xor(pd, m); }
    if (row < N_NODES){
      *(float4*)(h2 + (size_t)row*32 + 4*cg) = acc[j];
      if (cg == 0){ asrc[row] = ps; adst[row] = pd; }
    }
  }
}

// ---------------- conv2: wave/node; 8 edges per iter, float4 row loads, LDS-staged e ---
__global__ __launch_bounds__(256) void k_conv2(const unsigned* __restrict__ off,
    const int* __restrict__ csr_src, const float* __restrict__ h2,
    const float* __restrict__ asrc, const float* __restrict__ adst,
    const float* __restrict__ b2, float* __restrict__ hout)
{
  __shared__ float el[4][72];
  __shared__ int   il[4][72];
  int w    = threadIdx.x >> 6;
  int lane = threadIdx.x & 63;
  int n = blockIdx.x*4 + w;
  if (n >= N_NODES) return;
  unsigned s0 = off[n];
  int deg = (int)(off[n+1] - s0);
  float ad = adst[n];
  int cl = lane & 7;              // feature group: floats 4*cl..4*cl+3
  float4 acc = make_float4(0,0,0,0);
  float den = 0.f;

  if (deg <= 64){
    int idx = 0;
    float a = -1e30f;
    if (lane < deg){
      idx = csr_src[s0 + lane];
      a = leaky02(asrc[idx] + ad);
    }
    float m = a;
    #pragma unroll
    for (int mm = 32; mm >= 1; mm >>= 1) m = fmaxf(m, __shfl_xor(m, mm));
    float e = (lane < deg) ? __expf(a - m) : 0.f;
    el[w][lane] = e;
    il[w][lane] = idx;
    if (lane < 8){ el[w][64+lane] = 0.f; il[w][64+lane] = 0; }
    __builtin_amdgcn_wave_barrier();
    int g8 = lane >> 3;
    #pragma unroll 2
    for (int i = 0; i < deg; i += 8){
      int ii = i + g8;
      float es = el[w][ii];
      int s = il[w][ii];
      float4 hv = *(const float4*)(h2 + (size_t)s*32 + 4*cl);
      acc.x += es*hv.x; acc.y += es*hv.y; acc.z += es*hv.z; acc.w += es*hv.w;
      den += es;
    }
    #pragma unroll
    for (int mm = 8; mm <= 32; mm <<= 1){
      acc.x += __shfl_xor(acc.x, mm); acc.y += __shfl_xor(acc.y, mm);
      acc.z += __shfl_xor(acc.z, mm); acc.w += __shfl_xor(acc.w, mm);
      den   += __shfl_xor(den, mm);
    }
  } else {
    float m = -1e30f;
    for (int i = lane; i < deg; i += 64){
      int s = csr_src[s0 + i];
      m = fmaxf(m, leaky02(asrc[s] + ad));
    }
    #pragma unroll
    for (int mm = 32; mm >= 1; mm >>= 1) m = fmaxf(m, __shfl_xor(m, mm));
    for (int i = 0; i < deg; ++i){
      int s = csr_src[s0 + i];
      float a = leaky02(asrc[s] + ad);
      float ev = __expf(a - m);
      float4 hv = *(const float4*)(h2 + (size_t)s*32 + 4*cl);
      acc.x += ev*hv.x; acc.y += ev*hv.y; acc.z += ev*hv.z; acc.w += ev*hv.w;
      den += ev;
    }
  }
  if (lane < 8){
    float inv = 1.f/(den + 1e-16f);
    float4 bv = ((const float4*)b2)[cl];
    float4 o;
    o.x = acc.x*inv + bv.x; o.y = acc.y*inv + bv.y;
    o.z = acc.z*inv + bv.z; o.w = acc.w*inv + bv.w;
    *(float4*)(hout + (size_t)n*32 + 4*cl) = o;
  }
}

// ---------------- pool: one block per graph, contiguous segmented mean -----------------
__global__ __launch_bounds__(256) void k_pool(const int* __restrict__ batch,
    const float* __restrict__ hout, float* __restrict__ gmean)
{
  int g = blockIdx.x;
  int a = 0, b = N_NODES;
  while (a < b){ int mid = (a+b)>>1; if (batch[mid] < g) a = mid+1; else b = mid; }
  int lo = a;
  b = N_NODES;
  while (a < b){ int mid = (a+b)>>1; if (batch[mid] < g+1) a = mid+1; else b = mid; }
  int hi = a;
  int c = threadIdx.x & 31, rg = threadIdx.x >> 5;   // 8 row groups
  float s = 0.f;
  for (int r = lo + rg; r < hi; r += 8) s += hout[(size_t)r*32 + c];
  __shared__ float red[8][32];
  red[rg][c] = s;
  __syncthreads();
  if (rg == 0){
    float t = 0.f;
    #pragma unroll
    for (int k = 0; k < 8; ++k) t += red[k][c];
    gmean[g*32 + c] = t / fmaxf((float)(hi - lo), 1.0f);
  }
}

// ---------------- final MLP (64 graphs, 1 block) ---------------------------------------
__global__ void k_final(const float* __restrict__ gmean,
    const float* __restrict__ l1w, const float* __restrict__ l1b,
    const float* __restrict__ l2w, const float* __restrict__ l2b, float* __restrict__ out)
{
  int t = threadIdx.x;
  if (t >= NG) return;
  float g[32];
  #pragma unroll
  for (int j = 0; j < 32; ++j) g[j] = gmean[t*32 + j];
  float o = l2b[0];
  #pragma unroll
  for (int k = 0; k < 16; ++k){
    float hv = l1b[k];
    #pragma unroll
    for (int j = 0; j < 32; ++j) hv += g[j]*l1w[j*16 + k];
    o += eluf(hv) * l2w[k];
  }
  out[t] = o;
}

extern "C" void kernel_launch(void* const* d_in, const int* in_sizes, int n_in,
                              void* d_out, int out_size, void* d_ws, size_t ws_size,
                              hipStream_t stream) {
  const float* x     = (const float*)d_in[0];
  const int*   ei    = (const int*)  d_in[1];
  const int*   batch = (const int*)  d_in[2];
  const float* W1    = (const float*)d_in[3];
  const float* attS1 = (const float*)d_in[4];
  const float* attD1 = (const float*)d_in[5];
  const float* b1    = (const float*)d_in[6];
  const float* W2    = (const float*)d_in[7];
  const float* attS2 = (const float*)d_in[8];
  const float* attD2 = (const float*)d_in[9];
  const float* b2    = (const float*)d_in[10];
  const float* l1w   = (const float*)d_in[11];
  const float* l1b   = (const float*)d_in[12];
  const float* l2w   = (const float*)d_in[13];
  const float* l2b   = (const float*)d_in[14];
  float* out = (float*)d_out;

  char* w = (char*)d_ws;
  auto alloc = [&](size_t elems) -> void* {
    void* p = (void*)w;
    w += ((elems*4 + 255)/256)*256;
    return p;
  };
  unsigned* csr_off = (unsigned*)alloc(N_NODES + 1);
  unsigned* csr_wp  = (unsigned*)alloc(N_NODES);
  unsigned* deg     = (unsigned*)alloc(N_NODES);
  unsigned* bsum    = (unsigned*)alloc(SCAN_NB);
  unsigned* boff    = (unsigned*)alloc(SCAN_NB);
  int*      csr_src = (int*)     alloc(ETOT);
  float* h1    = (float*)alloc((size_t)N_NODES*128);
  float* asrc1 = (float*)alloc((size_t)N_NODES*4);
  float* adst1 = (float*)alloc((size_t)N_NODES*4);
  float* helu  = (float*)alloc((size_t)N_NODES*128);
  float* h2    = (float*)alloc((size_t)N_NODES*32);
  float* asrc2 = (float*)alloc(N_NODES);
  float* adst2 = (float*)alloc(N_NODES);
  float* hout  = (float*)alloc((size_t)N_NODES*32);
  float* gmean = (float*)alloc(NG*32);

  k_init_deg<<<SCAN_NB, 256, 0, stream>>>(deg);
  k_count   <<<(N_EDGES + 255)/256, 256, 0, stream>>>(ei, deg);
  k_scan1   <<<SCAN_NB, 256, 0, stream>>>(deg, bsum);
  k_scan2   <<<1, 256, 0, stream>>>(bsum, boff);
  k_scan3   <<<SCAN_NB, 256, 0, stream>>>(deg, boff, csr_off, csr_wp);
  k_scatter <<<(ETOT + 255)/256, 256, 0, stream>>>(ei, csr_wp, csr_src);

  k_gemm1<<<(N_NODES + 31)/32, 256, 0, stream>>>(x, W1, attS1, attD1, h1, asrc1, adst1);
  k_conv1<<<(N_NODES + 3)/4, 256, 0, stream>>>(csr_off, csr_src, h1, asrc1, adst1, b1, helu);
  k_gemm2<<<(N_NODES + 127)/128, 256, 0, stream>>>(helu, W2, attS2, attD2, h2, asrc2, adst2);
  k_conv2<<<(N_NODES + 3)/4, 256, 0, stream>>>(csr_off, csr_src, h2, asrc2, adst2, b2, hout);
  k_pool <<<NG, 256, 0, stream>>>(batch, hout, gmean);
  k_final<<<1, 64, 0, stream>>>(gmean, l1w, l1b, l2w, l2b, out);
}

// Round 5
// 278.429 us; speedup vs baseline: 3.0718x; 1.1254x over previous
//
#include <hip/hip_runtime.h>
#include <math.h>

#define N_NODES 50000
#define N_EDGES 800000
#define ETOT (N_EDGES + N_NODES)
#define NG 64
#define SCAN_NB ((N_NODES + 255)/256)   // 196

__device__ __forceinline__ float leaky02(float a){ return a > 0.f ? a : 0.2f*a; }
__device__ __forceinline__ float eluf(float v){ return v > 0.f ? v : expm1f(v); }

// ---------------- CSR build (by dst), edges = [E real] + [N self-loops] ----------------
__global__ void k_init_deg(unsigned* __restrict__ deg){
  int i = blockIdx.x*256 + threadIdx.x;
  if (i < N_NODES) deg[i] = 1u;            // self-loop
}

__global__ void k_count(const int* __restrict__ ei, unsigned* __restrict__ deg){
  int e = blockIdx.x*256 + threadIdx.x;
  if (e >= N_EDGES) return;
  atomicAdd(&deg[ei[N_EDGES + e]], 1u);
}

// multi-block exclusive scan of deg -> off, wp
__global__ __launch_bounds__(256) void k_scan1(const unsigned* __restrict__ deg,
                                               unsigned* __restrict__ bsum){
  int i = blockIdx.x*256 + threadIdx.x;
  unsigned v = (i < N_NODES) ? deg[i] : 0u;
  #pragma unroll
  for (int o = 32; o >= 1; o >>= 1) v += __shfl_xor(v, o);
  __shared__ unsigned ws[4];
  if ((threadIdx.x & 63) == 0) ws[threadIdx.x >> 6] = v;
  __syncthreads();
  if (threadIdx.x == 0) bsum[blockIdx.x] = ws[0] + ws[1] + ws[2] + ws[3];
}

__global__ __launch_bounds__(256) void k_scan2(const unsigned* __restrict__ bsum,
                                               unsigned* __restrict__ boff){
  __shared__ unsigned ts[256];
  int t = threadIdx.x;
  unsigned v = (t < SCAN_NB) ? bsum[t] : 0u;
  ts[t] = v; __syncthreads();
  for (int o = 1; o < 256; o <<= 1){
    unsigned u = (t >= o) ? ts[t-o] : 0u;
    __syncthreads();
    ts[t] += u;
    __syncthreads();
  }
  if (t < SCAN_NB) boff[t] = ts[t] - v;    // exclusive
}

__global__ __launch_bounds__(256) void k_scan3(const unsigned* __restrict__ deg,
    const unsigned* __restrict__ boff, unsigned* __restrict__ off, unsigned* __restrict__ wp){
  __shared__ unsigned ts[256];
  int t = threadIdx.x;
  int i = blockIdx.x*256 + t;
  unsigned v = (i < N_NODES) ? deg[i] : 0u;
  ts[t] = v; __syncthreads();
  for (int o = 1; o < 256; o <<= 1){
    unsigned u = (t >= o) ? ts[t-o] : 0u;
    __syncthreads();
    ts[t] += u;
    __syncthreads();
  }
  unsigned e = boff[blockIdx.x] + ts[t] - v;
  if (i < N_NODES){ off[i] = e; wp[i] = e; }
  if (i == 0) off[N_NODES] = (unsigned)ETOT;
}

__global__ void k_scatter(const int* __restrict__ ei, unsigned* __restrict__ wp,
                          int* __restrict__ csr_src){
  int e = blockIdx.x*256 + threadIdx.x;
  if (e >= ETOT) return;
  int s, d;
  if (e < N_EDGES){ s = ei[e]; d = ei[N_EDGES + e]; } else { s = e - N_EDGES; d = s; }
  unsigned pos = atomicAdd(&wp[d], 1u);
  csr_src[pos] = s;
}

// ---------------- GEMM1: h1 = x @ W1 (128x128) -----------------------------------------
// 128 rows/block, 2 K-phases of 64; thread tile 8 rows x 8 cols.
// ws: even/odd column-slot interleave so wv reads are 2-way (free); xs pad 68.
__global__ __launch_bounds__(256) void k_gemm1(const float* __restrict__ x,
    const float* __restrict__ W, const float* __restrict__ attS, const float* __restrict__ attD,
    float* __restrict__ h1, float* __restrict__ asrc, float* __restrict__ adst)
{
  __shared__ float ws[64*128];    // 32 KB
  __shared__ float xs[128*68];    // 34.8 KB
  int tid = threadIdx.x;
  int base = blockIdx.x * 128;
  int cg = tid & 15, rq = tid >> 4;        // 16 col-groups x 16 row-groups
  float4 acc[8][2];
  #pragma unroll
  for (int j = 0; j < 8; ++j){ acc[j][0] = make_float4(0,0,0,0); acc[j][1] = make_float4(0,0,0,0); }

  for (int p = 0; p < 2; ++p){
    if (p) __syncthreads();
    #pragma unroll
    for (int i = 0; i < 8; ++i){         // stage W[64k x 128c], swizzled slots
      int l = tid + i*256;
      int k = l >> 5, c4 = l & 31;
      float4 v = *(const float4*)(W + (size_t)(p*64 + k)*128 + 4*c4);
      int phys = (c4 >> 1) | ((c4 & 1) << 4);
      *(float4*)(ws + k*128 + 4*phys) = v;
    }
    #pragma unroll
    for (int i = 0; i < 8; ++i){         // stage x[128r x 64k]
      int l = tid + i*256;
      int r = l >> 4, c4 = l & 15;
      float4 v = make_float4(0,0,0,0);
      if (base + r < N_NODES) v = *(const float4*)(x + (size_t)(base+r)*128 + p*64 + 4*c4);
      *(float4*)(xs + r*68 + 4*c4) = v;
    }
    __syncthreads();
    #pragma unroll 1
    for (int kk = 0; kk < 16; ++kk){
      float4 xv[8], wv[4][2];
      #pragma unroll
      for (int j = 0; j < 8; ++j) xv[j] = *(const float4*)(xs + (rq*8 + j)*68 + 4*kk);
      #pragma unroll
      for (int t = 0; t < 4; ++t){
        wv[t][0] = *(const float4*)(ws + (4*kk + t)*128 + 4*cg);
        wv[t][1] = *(const float4*)(ws + (4*kk + t)*128 + 4*(cg + 16));
      }
      #pragma unroll
      for (int j = 0; j < 8; ++j){
        #pragma unroll
        for (int t = 0; t < 4; ++t){
          float xf = (t==0) ? xv[j].x : (t==1) ? xv[j].y : (t==2) ? xv[j].z : xv[j].w;
          #pragma unroll
          for (int u = 0; u < 2; ++u){
            acc[j][u].x += xf*wv[t][u].x; acc[j][u].y += xf*wv[t][u].y;
            acc[j][u].z += xf*wv[t][u].z; acc[j][u].w += xf*wv[t][u].w;
          }
        }
      }
    }
  }
  // epilogue: h1 + per-head alphas
  int hd = cg >> 2, lc = 8*(cg & 3);
  float s0v[8], s1v[8];
  #pragma unroll
  for (int j = 0; j < 8; ++j){
    float ps = 0.f, pd = 0.f;
    #pragma unroll
    for (int u = 0; u < 2; ++u){
      const float* aS = attS + hd*32 + lc + 4*u;
      const float* aD = attD + hd*32 + lc + 4*u;
      ps += acc[j][u].x*aS[0] + acc[j][u].y*aS[1] + acc[j][u].z*aS[2] + acc[j][u].w*aS[3];
      pd += acc[j][u].x*aD[0] + acc[j][u].y*aD[1] + acc[j][u].z*aD[2] + acc[j][u].w*aD[3];
    }
    ps += __shfl_xor(ps, 1); ps += __shfl_xor(ps, 2);
    pd += __shfl_xor(pd, 1); pd += __shfl_xor(pd, 2);
    s0v[j] = ps; s1v[j] = pd;
  }
  #pragma unroll
  for (int j = 0; j < 8; ++j){
    int row = base + rq*8 + j;
    if (row < N_NODES){
      *(float4*)(h1 + (size_t)row*128 + 8*cg)     = acc[j][0];
      *(float4*)(h1 + (size_t)row*128 + 8*cg + 4) = acc[j][1];
      if ((cg & 3) == 0){ asrc[row*4 + hd] = s0v[j]; adst[row*4 + hd] = s1v[j]; }
    }
  }
}

// ---------------- conv1: wave/node; 2 edges per iter, float4 row loads, LDS-staged e ---
__global__ __launch_bounds__(256) void k_conv1(const unsigned* __restrict__ off,
    const int* __restrict__ csr_src, const float* __restrict__ h1,
    const float* __restrict__ asrc, const float* __restrict__ adst,
    const float* __restrict__ b1, float* __restrict__ helu)
{
  __shared__ float4 eh4[4][68];   // [wave][edge] -> e for heads 0..3
  __shared__ int    idxs[4][68];
  int w    = threadIdx.x >> 6;
  int lane = threadIdx.x & 63;
  int n = blockIdx.x*4 + w;
  if (n >= N_NODES) return;
  unsigned s0 = off[n];
  int deg = (int)(off[n+1] - s0);
  float4 ad = *(const float4*)(adst + (size_t)n*4);
  int cl = lane & 31;             // feature group: floats 4*cl..4*cl+3
  int h  = cl >> 3;               // head of this feature group
  float4 acc = make_float4(0,0,0,0);
  float den = 0.f;

  if (deg <= 64){
    int idx = 0;
    float a0=-1e30f, a1=-1e30f, a2=-1e30f, a3=-1e30f;
    if (lane < deg){
      idx = csr_src[s0 + lane];
      float4 as = *(const float4*)(asrc + (size_t)idx*4);
      a0 = leaky02(as.x + ad.x); a1 = leaky02(as.y + ad.y);
      a2 = leaky02(as.z + ad.z); a3 = leaky02(as.w + ad.w);
    }
    float m0=a0, m1=a1, m2=a2, m3=a3;
    #pragma unroll
    for (int m = 32; m >= 1; m >>= 1){
      m0 = fmaxf(m0, __shfl_xor(m0, m)); m1 = fmaxf(m1, __shfl_xor(m1, m));
      m2 = fmaxf(m2, __shfl_xor(m2, m)); m3 = fmaxf(m3, __shfl_xor(m3, m));
    }
    float4 ev = make_float4(0,0,0,0);
    if (lane < deg){
      ev.x = __expf(a0-m0); ev.y = __expf(a1-m1);
      ev.z = __expf(a2-m2); ev.w = __expf(a3-m3);
    }
    eh4[w][lane] = ev;
    idxs[w][lane] = idx;
    if (lane < 4){ eh4[w][64+lane] = make_float4(0,0,0,0); idxs[w][64+lane] = 0; }
    __builtin_amdgcn_wave_barrier();   // wave-coherent LDS: in-order DS, no s_barrier
    int half = lane >> 5;
    #pragma unroll 4
    for (int i = 0; i < deg; i += 2){
      int ii = i + half;
      float es = ((const float*)&eh4[w][ii])[h];
      int s = idxs[w][ii];
      float4 hv = *(const float4*)(h1 + (size_t)s*128 + 4*cl);
      acc.x += es*hv.x; acc.y += es*hv.y; acc.z += es*hv.z; acc.w += es*hv.w;
      den += es;
    }
    acc.x += __shfl_xor(acc.x, 32); acc.y += __shfl_xor(acc.y, 32);
    acc.z += __shfl_xor(acc.z, 32); acc.w += __shfl_xor(acc.w, 32);
    den   += __shfl_xor(den, 32);
  } else {
    float m0=-1e30f, m1=-1e30f, m2=-1e30f, m3=-1e30f;
    for (int i = lane; i < deg; i += 64){
      int s = csr_src[s0 + i];
      float4 as = *(const float4*)(asrc + (size_t)s*4);
      m0 = fmaxf(m0, leaky02(as.x + ad.x)); m1 = fmaxf(m1, leaky02(as.y + ad.y));
      m2 = fmaxf(m2, leaky02(as.z + ad.z)); m3 = fmaxf(m3, leaky02(as.w + ad.w));
    }
    #pragma unroll
    for (int m = 32; m >= 1; m >>= 1){
      m0 = fmaxf(m0, __shfl_xor(m0, m)); m1 = fmaxf(m1, __shfl_xor(m1, m));
      m2 = fmaxf(m2, __shfl_xor(m2, m)); m3 = fmaxf(m3, __shfl_xor(m3, m));
    }
    float mh  = (h==0) ? m0 : (h==1) ? m1 : (h==2) ? m2 : m3;
    float adh = (h==0) ? ad.x : (h==1) ? ad.y : (h==2) ? ad.z : ad.w;
    for (int i = 0; i < deg; ++i){
      int s = csr_src[s0 + i];
      float a = leaky02(asrc[s*4 + h] + adh);
      float ev = __expf(a - mh);
      float4 hv = *(const float4*)(h1 + (size_t)s*128 + 4*cl);
      acc.x += ev*hv.x; acc.y += ev*hv.y; acc.z += ev*hv.z; acc.w += ev*hv.w;
      den += ev;
    }
  }
  if (lane < 32){
    float inv = 1.f/(den + 1e-16f);
    float4 bv = ((const float4*)b1)[cl];
    float4 o;
    o.x = eluf(acc.x*inv + bv.x); o.y = eluf(acc.y*inv + bv.y);
    o.z = eluf(acc.z*inv + bv.z); o.w = eluf(acc.w*inv + bv.w);
    *(float4*)(helu + (size_t)n*128 + 4*cl) = o;
  }
}

// ---------------- GEMM2: h2 = helu @ W2 (128x32) ---------------------------------------
// 128 rows/block, 2 K-phases of 64; thread tile 4 rows x 4 cols. 43 KB LDS -> 3 blk/CU.
__global__ __launch_bounds__(256) void k_gemm2(const float* __restrict__ xin,
    const float* __restrict__ W, const float* __restrict__ attS, const float* __restrict__ attD,
    float* __restrict__ h2, float* __restrict__ asrc, float* __restrict__ adst)
{
  __shared__ float ws[64*32];     // 8 KB
  __shared__ float xs[128*68];    // 34.8 KB
  int tid = threadIdx.x;
  int base = blockIdx.x * 128;
  int cg = tid & 7, rq = tid >> 3;         // 8 col-groups x 32 row-groups
  float4 acc[4];
  #pragma unroll
  for (int j = 0; j < 4; ++j) acc[j] = make_float4(0,0,0,0);

  for (int p = 0; p < 2; ++p){
    if (p) __syncthreads();
    #pragma unroll
    for (int i = 0; i < 2; ++i){         // stage W2[64k x 32c]
      int l = tid + i*256;
      int k = l >> 3, c4 = l & 7;
      *(float4*)(ws + k*32 + 4*c4) = *(const float4*)(W + (size_t)(p*64 + k)*32 + 4*c4);
    }
    #pragma unroll
    for (int i = 0; i < 8; ++i){         // stage xin[128r x 64k]
      int l = tid + i*256;
      int r = l >> 4, c4 = l & 15;
      float4 v = make_float4(0,0,0,0);
      if (base + r < N_NODES) v = *(const float4*)(xin + (size_t)(base+r)*128 + p*64 + 4*c4);
      *(float4*)(xs + r*68 + 4*c4) = v;
    }
    __syncthreads();
    #pragma unroll 1
    for (int kk = 0; kk < 16; ++kk){
      float4 xv[4], wv[4];
      #pragma unroll
      for (int j = 0; j < 4; ++j) xv[j] = *(const float4*)(xs + (rq*4 + j)*68 + 4*kk);
      #pragma unroll
      for (int t = 0; t < 4; ++t) wv[t] = *(const float4*)(ws + (4*kk + t)*32 + 4*cg);
      #pragma unroll
      for (int j = 0; j < 4; ++j){
        #pragma unroll
        for (int t = 0; t < 4; ++t){
          float xf = (t==0) ? xv[j].x : (t==1) ? xv[j].y : (t==2) ? xv[j].z : xv[j].w;
          acc[j].x += xf*wv[t].x; acc[j].y += xf*wv[t].y;
          acc[j].z += xf*wv[t].z; acc[j].w += xf*wv[t].w;
        }
      }
    }
  }
  // epilogue
  float psv[4], pdv[4];
  #pragma unroll
  for (int j = 0; j < 4; ++j){
    const float* aS = attS + 4*cg;
    const float* aD = attD + 4*cg;
    float ps = acc[j].x*aS[0] + acc[j].y*aS[1] + acc[j].z*aS[2] + acc[j].w*aS[3];
    float pd = acc[j].x*aD[0] + acc[j].y*aD[1] + acc[j].z*aD[2] + acc[j].w*aD[3];
    ps += __shfl_xor(ps, 1); ps += __shfl_xor(ps, 2); ps += __shfl_xor(ps, 4);
    pd += __shfl_xor(pd, 1); pd += __shfl_xor(pd, 2); pd += __shfl_xor(pd, 4);
    psv[j] = ps; pdv[j] = pd;
  }
  #pragma unroll
  for (int j = 0; j < 4; ++j){
    int row = base + rq*4 + j;
    if (row < N_NODES){
      *(float4*)(h2 + (size_t)row*32 + 4*cg) = acc[j];
      if (cg == 0){ asrc[row] = psv[j]; adst[row] = pdv[j]; }
    }
  }
}

// ---------------- conv2: wave/node; 8 edges per iter, float4 row loads, LDS-staged e ---
__global__ __launch_bounds__(256) void k_conv2(const unsigned* __restrict__ off,
    const int* __restrict__ csr_src, const float* __restrict__ h2,
    const float* __restrict__ asrc, const float* __restrict__ adst,
    const float* __restrict__ b2, float* __restrict__ hout)
{
  __shared__ float el[4][72];
  __shared__ int   il[4][72];
  int w    = threadIdx.x >> 6;
  int lane = threadIdx.x & 63;
  int n = blockIdx.x*4 + w;
  if (n >= N_NODES) return;
  unsigned s0 = off[n];
  int deg = (int)(off[n+1] - s0);
  float ad = adst[n];
  int cl = lane & 7;              // feature group: floats 4*cl..4*cl+3
  float4 acc = make_float4(0,0,0,0);
  float den = 0.f;

  if (deg <= 64){
    int idx = 0;
    float a = -1e30f;
    if (lane < deg){
      idx = csr_src[s0 + lane];
      a = leaky02(asrc[idx] + ad);
    }
    float m = a;
    #pragma unroll
    for (int mm = 32; mm >= 1; mm >>= 1) m = fmaxf(m, __shfl_xor(m, mm));
    float e = (lane < deg) ? __expf(a - m) : 0.f;
    el[w][lane] = e;
    il[w][lane] = idx;
    if (lane < 8){ el[w][64+lane] = 0.f; il[w][64+lane] = 0; }
    __builtin_amdgcn_wave_barrier();
    int g8 = lane >> 3;
    #pragma unroll 2
    for (int i = 0; i < deg; i += 8){
      int ii = i + g8;
      float es = el[w][ii];
      int s = il[w][ii];
      float4 hv = *(const float4*)(h2 + (size_t)s*32 + 4*cl);
      acc.x += es*hv.x; acc.y += es*hv.y; acc.z += es*hv.z; acc.w += es*hv.w;
      den += es;
    }
    #pragma unroll
    for (int mm = 8; mm <= 32; mm <<= 1){
      acc.x += __shfl_xor(acc.x, mm); acc.y += __shfl_xor(acc.y, mm);
      acc.z += __shfl_xor(acc.z, mm); acc.w += __shfl_xor(acc.w, mm);
      den   += __shfl_xor(den, mm);
    }
  } else {
    float m = -1e30f;
    for (int i = lane; i < deg; i += 64){
      int s = csr_src[s0 + i];
      m = fmaxf(m, leaky02(asrc[s] + ad));
    }
    #pragma unroll
    for (int mm = 32; mm >= 1; mm >>= 1) m = fmaxf(m, __shfl_xor(m, mm));
    for (int i = 0; i < deg; ++i){
      int s = csr_src[s0 + i];
      float a = leaky02(asrc[s] + ad);
      float ev = __expf(a - m);
      float4 hv = *(const float4*)(h2 + (size_t)s*32 + 4*cl);
      acc.x += ev*hv.x; acc.y += ev*hv.y; acc.z += ev*hv.z; acc.w += ev*hv.w;
      den += ev;
    }
  }
  if (lane < 8){
    float inv = 1.f/(den + 1e-16f);
    float4 bv = ((const float4*)b2)[cl];
    float4 o;
    o.x = acc.x*inv + bv.x; o.y = acc.y*inv + bv.y;
    o.z = acc.z*inv + bv.z; o.w = acc.w*inv + bv.w;
    *(float4*)(hout + (size_t)n*32 + 4*cl) = o;
  }
}

// ---------------- pool: one block per graph, contiguous segmented mean -----------------
__global__ __launch_bounds__(256) void k_pool(const int* __restrict__ batch,
    const float* __restrict__ hout, float* __restrict__ gmean)
{
  int g = blockIdx.x;
  int a = 0, b = N_NODES;
  while (a < b){ int mid = (a+b)>>1; if (batch[mid] < g) a = mid+1; else b = mid; }
  int lo = a;
  b = N_NODES;
  while (a < b){ int mid = (a+b)>>1; if (batch[mid] < g+1) a = mid+1; else b = mid; }
  int hi = a;
  int c = threadIdx.x & 31, rg = threadIdx.x >> 5;   // 8 row groups
  float s = 0.f;
  for (int r = lo + rg; r < hi; r += 8) s += hout[(size_t)r*32 + c];
  __shared__ float red[8][32];
  red[rg][c] = s;
  __syncthreads();
  if (rg == 0){
    float t = 0.f;
    #pragma unroll
    for (int k = 0; k < 8; ++k) t += red[k][c];
    gmean[g*32 + c] = t / fmaxf((float)(hi - lo), 1.0f);
  }
}

// ---------------- final MLP (64 graphs, 1 block) ---------------------------------------
__global__ void k_final(const float* __restrict__ gmean,
    const float* __restrict__ l1w, const float* __restrict__ l1b,
    const float* __restrict__ l2w, const float* __restrict__ l2b, float* __restrict__ out)
{
  int t = threadIdx.x;
  if (t >= NG) return;
  float g[32];
  #pragma unroll
  for (int j = 0; j < 32; ++j) g[j] = gmean[t*32 + j];
  float o = l2b[0];
  #pragma unroll
  for (int k = 0; k < 16; ++k){
    float hv = l1b[k];
    #pragma unroll
    for (int j = 0; j < 32; ++j) hv += g[j]*l1w[j*16 + k];
    o += eluf(hv) * l2w[k];
  }
  out[t] = o;
}

extern "C" void kernel_launch(void* const* d_in, const int* in_sizes, int n_in,
                              void* d_out, int out_size, void* d_ws, size_t ws_size,
                              hipStream_t stream) {
  const float* x     = (const float*)d_in[0];
  const int*   ei    = (const int*)  d_in[1];
  const int*   batch = (const int*)  d_in[2];
  const float* W1    = (const float*)d_in[3];
  const float* attS1 = (const float*)d_in[4];
  const float* attD1 = (const float*)d_in[5];
  const float* b1    = (const float*)d_in[6];
  const float* W2    = (const float*)d_in[7];
  const float* attS2 = (const float*)d_in[8];
  const float* attD2 = (const float*)d_in[9];
  const float* b2    = (const float*)d_in[10];
  const float* l1w   = (const float*)d_in[11];
  const float* l1b   = (const float*)d_in[12];
  const float* l2w   = (const float*)d_in[13];
  const float* l2b   = (const float*)d_in[14];
  float* out = (float*)d_out;

  char* w = (char*)d_ws;
  auto alloc = [&](size_t elems) -> void* {
    void* p = (void*)w;
    w += ((elems*4 + 255)/256)*256;
    return p;
  };
  unsigned* csr_off = (unsigned*)alloc(N_NODES + 1);
  unsigned* csr_wp  = (unsigned*)alloc(N_NODES);
  unsigned* deg     = (unsigned*)alloc(N_NODES);
  unsigned* bsum    = (unsigned*)alloc(SCAN_NB);
  unsigned* boff    = (unsigned*)alloc(SCAN_NB);
  int*      csr_src = (int*)     alloc(ETOT);
  float* h1    = (float*)alloc((size_t)N_NODES*128);
  float* asrc1 = (float*)alloc((size_t)N_NODES*4);
  float* adst1 = (float*)alloc((size_t)N_NODES*4);
  float* helu  = (float*)alloc((size_t)N_NODES*128);
  float* h2    = (float*)alloc((size_t)N_NODES*32);
  float* asrc2 = (float*)alloc(N_NODES);
  float* adst2 = (float*)alloc(N_NODES);
  float* hout  = (float*)alloc((size_t)N_NODES*32);
  float* gmean = (float*)alloc(NG*32);

  k_init_deg<<<SCAN_NB, 256, 0, stream>>>(deg);
  k_count   <<<(N_EDGES + 255)/256, 256, 0, stream>>>(ei, deg);
  k_scan1   <<<SCAN_NB, 256, 0, stream>>>(deg, bsum);
  k_scan2   <<<1, 256, 0, stream>>>(bsum, boff);
  k_scan3   <<<SCAN_NB, 256, 0, stream>>>(deg, boff, csr_off, csr_wp);
  k_scatter <<<(ETOT + 255)/256, 256, 0, stream>>>(ei, csr_wp, csr_src);

  k_gemm1<<<(N_NODES + 127)/128, 256, 0, stream>>>(x, W1, attS1, attD1, h1, asrc1, adst1);
  k_conv1<<<(N_NODES + 3)/4, 256, 0, stream>>>(csr_off, csr_src, h1, asrc1, adst1, b1, helu);
  k_gemm2<<<(N_NODES + 127)/128, 256, 0, stream>>>(helu, W2, attS2, attD2, h2, asrc2, adst2);
  k_conv2<<<(N_NODES + 3)/4, 256, 0, stream>>>(csr_off, csr_src, h2, asrc2, adst2, b2, hout);
  k_pool <<<NG, 256, 0, stream>>>(batch, hout, gmean);
  k_final<<<1, 64, 0, stream>>>(gmean, l1w, l1b, l2w, l2b, out);
}

// Round 6
// 253.542 us; speedup vs baseline: 3.3733x; 1.0982x over previous
//
#include <hip/hip_runtime.h>
#include <math.h>

#define N_NODES 50000
#define N_EDGES 800000
#define ETOT (N_EDGES + N_NODES)
#define NG 64
#define SCAN_NB ((N_NODES + 255)/256)   // 196

__device__ __forceinline__ float leaky02(float a){ return a > 0.f ? a : 0.2f*a; }
__device__ __forceinline__ float eluf(float v){ return v > 0.f ? v : expm1f(v); }

// round-to-nearest-even f32->bf16, packed pair (a in low half, b in high half)
__device__ __forceinline__ unsigned pack_bf16(float a, float b){
  unsigned ua = __float_as_uint(a); ua += 0x7fffu + ((ua >> 16) & 1u);
  unsigned ub = __float_as_uint(b); ub += 0x7fffu + ((ub >> 16) & 1u);
  return (ua >> 16) | (ub & 0xffff0000u);
}
__device__ __forceinline__ float bf_lo(unsigned v){ return __uint_as_float(v << 16); }
__device__ __forceinline__ float bf_hi(unsigned v){ return __uint_as_float(v & 0xffff0000u); }

// ---------------- CSR build (by dst), edges = [E real] + [N self-loops] ----------------
__global__ void k_init_deg(unsigned* __restrict__ deg){
  int i = blockIdx.x*256 + threadIdx.x;
  if (i < N_NODES) deg[i] = 1u;            // self-loop
}

__global__ void k_count(const int* __restrict__ ei, unsigned* __restrict__ deg){
  int e = blockIdx.x*256 + threadIdx.x;
  if (e >= N_EDGES) return;
  atomicAdd(&deg[ei[N_EDGES + e]], 1u);
}

// multi-block exclusive scan of deg -> off, wp
__global__ __launch_bounds__(256) void k_scan1(const unsigned* __restrict__ deg,
                                               unsigned* __restrict__ bsum){
  int i = blockIdx.x*256 + threadIdx.x;
  unsigned v = (i < N_NODES) ? deg[i] : 0u;
  #pragma unroll
  for (int o = 32; o >= 1; o >>= 1) v += __shfl_xor(v, o);
  __shared__ unsigned ws[4];
  if ((threadIdx.x & 63) == 0) ws[threadIdx.x >> 6] = v;
  __syncthreads();
  if (threadIdx.x == 0) bsum[blockIdx.x] = ws[0] + ws[1] + ws[2] + ws[3];
}

__global__ __launch_bounds__(256) void k_scan2(const unsigned* __restrict__ bsum,
                                               unsigned* __restrict__ boff){
  __shared__ unsigned ts[256];
  int t = threadIdx.x;
  unsigned v = (t < SCAN_NB) ? bsum[t] : 0u;
  ts[t] = v; __syncthreads();
  for (int o = 1; o < 256; o <<= 1){
    unsigned u = (t >= o) ? ts[t-o] : 0u;
    __syncthreads();
    ts[t] += u;
    __syncthreads();
  }
  if (t < SCAN_NB) boff[t] = ts[t] - v;    // exclusive
}

__global__ __launch_bounds__(256) void k_scan3(const unsigned* __restrict__ deg,
    const unsigned* __restrict__ boff, unsigned* __restrict__ off, unsigned* __restrict__ wp){
  __shared__ unsigned ts[256];
  int t = threadIdx.x;
  int i = blockIdx.x*256 + t;
  unsigned v = (i < N_NODES) ? deg[i] : 0u;
  ts[t] = v; __syncthreads();
  for (int o = 1; o < 256; o <<= 1){
    unsigned u = (t >= o) ? ts[t-o] : 0u;
    __syncthreads();
    ts[t] += u;
    __syncthreads();
  }
  unsigned e = boff[blockIdx.x] + ts[t] - v;
  if (i < N_NODES){ off[i] = e; wp[i] = e; }
  if (i == 0) off[N_NODES] = (unsigned)ETOT;
}

__global__ void k_scatter(const int* __restrict__ ei, unsigned* __restrict__ wp,
                          int* __restrict__ csr_src){
  int e = blockIdx.x*256 + threadIdx.x;
  if (e >= ETOT) return;
  int s, d;
  if (e < N_EDGES){ s = ei[e]; d = ei[N_EDGES + e]; } else { s = e - N_EDGES; d = s; }
  unsigned pos = atomicAdd(&wp[d], 1u);
  csr_src[pos] = s;
}

// ---------------- GEMM1: h1 = x @ W1 (128x128), h1 stored bf16-packed ------------------
__global__ __launch_bounds__(256) void k_gemm1(const float* __restrict__ x,
    const float* __restrict__ W, const float* __restrict__ attS, const float* __restrict__ attD,
    unsigned* __restrict__ h1b, float* __restrict__ asrc, float* __restrict__ adst)
{
  __shared__ float ws[64*128];    // 32 KB
  __shared__ float xs[128*68];    // 34.8 KB
  int tid = threadIdx.x;
  int base = blockIdx.x * 128;
  int cg = tid & 15, rq = tid >> 4;        // 16 col-groups x 16 row-groups
  float4 acc[8][2];
  #pragma unroll
  for (int j = 0; j < 8; ++j){ acc[j][0] = make_float4(0,0,0,0); acc[j][1] = make_float4(0,0,0,0); }

  for (int p = 0; p < 2; ++p){
    if (p) __syncthreads();
    #pragma unroll
    for (int i = 0; i < 8; ++i){         // stage W[64k x 128c], swizzled slots
      int l = tid + i*256;
      int k = l >> 5, c4 = l & 31;
      float4 v = *(const float4*)(W + (size_t)(p*64 + k)*128 + 4*c4);
      int phys = (c4 >> 1) | ((c4 & 1) << 4);
      *(float4*)(ws + k*128 + 4*phys) = v;
    }
    #pragma unroll
    for (int i = 0; i < 8; ++i){         // stage x[128r x 64k]
      int l = tid + i*256;
      int r = l >> 4, c4 = l & 15;
      float4 v = make_float4(0,0,0,0);
      if (base + r < N_NODES) v = *(const float4*)(x + (size_t)(base+r)*128 + p*64 + 4*c4);
      *(float4*)(xs + r*68 + 4*c4) = v;
    }
    __syncthreads();
    #pragma unroll 1
    for (int kk = 0; kk < 16; ++kk){
      float4 xv[8], wv[4][2];
      #pragma unroll
      for (int j = 0; j < 8; ++j) xv[j] = *(const float4*)(xs + (rq*8 + j)*68 + 4*kk);
      #pragma unroll
      for (int t = 0; t < 4; ++t){
        wv[t][0] = *(const float4*)(ws + (4*kk + t)*128 + 4*cg);
        wv[t][1] = *(const float4*)(ws + (4*kk + t)*128 + 4*(cg + 16));
      }
      #pragma unroll
      for (int j = 0; j < 8; ++j){
        #pragma unroll
        for (int t = 0; t < 4; ++t){
          float xf = (t==0) ? xv[j].x : (t==1) ? xv[j].y : (t==2) ? xv[j].z : xv[j].w;
          #pragma unroll
          for (int u = 0; u < 2; ++u){
            acc[j][u].x += xf*wv[t][u].x; acc[j][u].y += xf*wv[t][u].y;
            acc[j][u].z += xf*wv[t][u].z; acc[j][u].w += xf*wv[t][u].w;
          }
        }
      }
    }
  }
  // epilogue: bf16 h1 + per-head alphas (f32)
  int hd = cg >> 2, lc = 8*(cg & 3);
  float s0v[8], s1v[8];
  #pragma unroll
  for (int j = 0; j < 8; ++j){
    float ps = 0.f, pd = 0.f;
    #pragma unroll
    for (int u = 0; u < 2; ++u){
      const float* aS = attS + hd*32 + lc + 4*u;
      const float* aD = attD + hd*32 + lc + 4*u;
      ps += acc[j][u].x*aS[0] + acc[j][u].y*aS[1] + acc[j][u].z*aS[2] + acc[j][u].w*aS[3];
      pd += acc[j][u].x*aD[0] + acc[j][u].y*aD[1] + acc[j][u].z*aD[2] + acc[j][u].w*aD[3];
    }
    ps += __shfl_xor(ps, 1); ps += __shfl_xor(ps, 2);
    pd += __shfl_xor(pd, 1); pd += __shfl_xor(pd, 2);
    s0v[j] = ps; s1v[j] = pd;
  }
  #pragma unroll
  for (int j = 0; j < 8; ++j){
    int row = base + rq*8 + j;
    if (row < N_NODES){
      uint4 pk;
      pk.x = pack_bf16(acc[j][0].x, acc[j][0].y);
      pk.y = pack_bf16(acc[j][0].z, acc[j][0].w);
      pk.z = pack_bf16(acc[j][1].x, acc[j][1].y);
      pk.w = pack_bf16(acc[j][1].z, acc[j][1].w);
      *(uint4*)(h1b + (size_t)row*64 + 4*cg) = pk;
      if ((cg & 3) == 0){ asrc[row*4 + hd] = s0v[j]; adst[row*4 + hd] = s1v[j]; }
    }
  }
}

// ---------------- conv1: wave/node; 2 edges/iter, bf16 row gathers, LDS-staged e -------
__global__ __launch_bounds__(256) void k_conv1(const unsigned* __restrict__ off,
    const int* __restrict__ csr_src, const unsigned* __restrict__ h1b,
    const float* __restrict__ asrc, const float* __restrict__ adst,
    const float* __restrict__ b1, float* __restrict__ helu)
{
  __shared__ float4 eh4[4][68];   // [wave][edge] -> e for heads 0..3
  __shared__ int    idxs[4][68];
  int w    = threadIdx.x >> 6;
  int lane = threadIdx.x & 63;
  int n = blockIdx.x*4 + w;
  if (n >= N_NODES) return;
  unsigned s0 = off[n];
  int deg = (int)(off[n+1] - s0);
  float4 ad = *(const float4*)(adst + (size_t)n*4);
  int cl = lane & 31;             // feature group: floats 4*cl..4*cl+3
  int h  = cl >> 3;               // head of this feature group
  float4 acc = make_float4(0,0,0,0);
  float den = 0.f;

  if (deg <= 64){
    int idx = 0;
    float a0=-1e30f, a1=-1e30f, a2=-1e30f, a3=-1e30f;
    if (lane < deg){
      idx = csr_src[s0 + lane];
      float4 as = *(const float4*)(asrc + (size_t)idx*4);
      a0 = leaky02(as.x + ad.x); a1 = leaky02(as.y + ad.y);
      a2 = leaky02(as.z + ad.z); a3 = leaky02(as.w + ad.w);
    }
    float m0=a0, m1=a1, m2=a2, m3=a3;
    #pragma unroll
    for (int m = 32; m >= 1; m >>= 1){
      m0 = fmaxf(m0, __shfl_xor(m0, m)); m1 = fmaxf(m1, __shfl_xor(m1, m));
      m2 = fmaxf(m2, __shfl_xor(m2, m)); m3 = fmaxf(m3, __shfl_xor(m3, m));
    }
    float4 ev = make_float4(0,0,0,0);
    if (lane < deg){
      ev.x = __expf(a0-m0); ev.y = __expf(a1-m1);
      ev.z = __expf(a2-m2); ev.w = __expf(a3-m3);
    }
    eh4[w][lane] = ev;
    idxs[w][lane] = idx;
    if (lane < 4){ eh4[w][64+lane] = make_float4(0,0,0,0); idxs[w][64+lane] = 0; }
    __builtin_amdgcn_wave_barrier();   // wave-coherent LDS: in-order DS, no s_barrier
    int half = lane >> 5;
    #pragma unroll 4
    for (int i = 0; i < deg; i += 2){
      int ii = i + half;
      float es = ((const float*)&eh4[w][ii])[h];
      int s = idxs[w][ii];
      uint2 hb = *(const uint2*)(h1b + (size_t)s*64 + 2*cl);
      acc.x += es*bf_lo(hb.x); acc.y += es*bf_hi(hb.x);
      acc.z += es*bf_lo(hb.y); acc.w += es*bf_hi(hb.y);
      den += es;
    }
    acc.x += __shfl_xor(acc.x, 32); acc.y += __shfl_xor(acc.y, 32);
    acc.z += __shfl_xor(acc.z, 32); acc.w += __shfl_xor(acc.w, 32);
    den   += __shfl_xor(den, 32);
  } else {
    float m0=-1e30f, m1=-1e30f, m2=-1e30f, m3=-1e30f;
    for (int i = lane; i < deg; i += 64){
      int s = csr_src[s0 + i];
      float4 as = *(const float4*)(asrc + (size_t)s*4);
      m0 = fmaxf(m0, leaky02(as.x + ad.x)); m1 = fmaxf(m1, leaky02(as.y + ad.y));
      m2 = fmaxf(m2, leaky02(as.z + ad.z)); m3 = fmaxf(m3, leaky02(as.w + ad.w));
    }
    #pragma unroll
    for (int m = 32; m >= 1; m >>= 1){
      m0 = fmaxf(m0, __shfl_xor(m0, m)); m1 = fmaxf(m1, __shfl_xor(m1, m));
      m2 = fmaxf(m2, __shfl_xor(m2, m)); m3 = fmaxf(m3, __shfl_xor(m3, m));
    }
    float mh  = (h==0) ? m0 : (h==1) ? m1 : (h==2) ? m2 : m3;
    float adh = (h==0) ? ad.x : (h==1) ? ad.y : (h==2) ? ad.z : ad.w;
    for (int i = 0; i < deg; ++i){
      int s = csr_src[s0 + i];
      float a = leaky02(asrc[s*4 + h] + adh);
      float ev = __expf(a - mh);
      uint2 hb = *(const uint2*)(h1b + (size_t)s*64 + 2*cl);
      acc.x += ev*bf_lo(hb.x); acc.y += ev*bf_hi(hb.x);
      acc.z += ev*bf_lo(hb.y); acc.w += ev*bf_hi(hb.y);
      den += ev;
    }
  }
  if (lane < 32){
    float inv = 1.f/(den + 1e-16f);
    float4 bv = ((const float4*)b1)[cl];
    float4 o;
    o.x = eluf(acc.x*inv + bv.x); o.y = eluf(acc.y*inv + bv.y);
    o.z = eluf(acc.z*inv + bv.z); o.w = eluf(acc.w*inv + bv.w);
    *(float4*)(helu + (size_t)n*128 + 4*cl) = o;
  }
}

// ---------------- GEMM2: h2 = helu @ W2 (128x32), h2 stored bf16-packed ----------------
__global__ __launch_bounds__(256) void k_gemm2(const float* __restrict__ xin,
    const float* __restrict__ W, const float* __restrict__ attS, const float* __restrict__ attD,
    unsigned* __restrict__ h2b, float* __restrict__ asrc, float* __restrict__ adst)
{
  __shared__ float ws[64*32];     // 8 KB
  __shared__ float xs[128*68];    // 34.8 KB
  int tid = threadIdx.x;
  int base = blockIdx.x * 128;
  int cg = tid & 7, rq = tid >> 3;         // 8 col-groups x 32 row-groups
  float4 acc[4];
  #pragma unroll
  for (int j = 0; j < 4; ++j) acc[j] = make_float4(0,0,0,0);

  for (int p = 0; p < 2; ++p){
    if (p) __syncthreads();
    #pragma unroll
    for (int i = 0; i < 2; ++i){         // stage W2[64k x 32c]
      int l = tid + i*256;
      int k = l >> 3, c4 = l & 7;
      *(float4*)(ws + k*32 + 4*c4) = *(const float4*)(W + (size_t)(p*64 + k)*32 + 4*c4);
    }
    #pragma unroll
    for (int i = 0; i < 8; ++i){         // stage xin[128r x 64k]
      int l = tid + i*256;
      int r = l >> 4, c4 = l & 15;
      float4 v = make_float4(0,0,0,0);
      if (base + r < N_NODES) v = *(const float4*)(xin + (size_t)(base+r)*128 + p*64 + 4*c4);
      *(float4*)(xs + r*68 + 4*c4) = v;
    }
    __syncthreads();
    #pragma unroll 1
    for (int kk = 0; kk < 16; ++kk){
      float4 xv[4], wv[4];
      #pragma unroll
      for (int j = 0; j < 4; ++j) xv[j] = *(const float4*)(xs + (rq*4 + j)*68 + 4*kk);
      #pragma unroll
      for (int t = 0; t < 4; ++t) wv[t] = *(const float4*)(ws + (4*kk + t)*32 + 4*cg);
      #pragma unroll
      for (int j = 0; j < 4; ++j){
        #pragma unroll
        for (int t = 0; t < 4; ++t){
          float xf = (t==0) ? xv[j].x : (t==1) ? xv[j].y : (t==2) ? xv[j].z : xv[j].w;
          acc[j].x += xf*wv[t].x; acc[j].y += xf*wv[t].y;
          acc[j].z += xf*wv[t].z; acc[j].w += xf*wv[t].w;
        }
      }
    }
  }
  // epilogue
  float psv[4], pdv[4];
  #pragma unroll
  for (int j = 0; j < 4; ++j){
    const float* aS = attS + 4*cg;
    const float* aD = attD + 4*cg;
    float ps = acc[j].x*aS[0] + acc[j].y*aS[1] + acc[j].z*aS[2] + acc[j].w*aS[3];
    float pd = acc[j].x*aD[0] + acc[j].y*aD[1] + acc[j].z*aD[2] + acc[j].w*aD[3];
    ps += __shfl_xor(ps, 1); ps += __shfl_xor(ps, 2); ps += __shfl_xor(ps, 4);
    pd += __shfl_xor(pd, 1); pd += __shfl_xor(pd, 2); pd += __shfl_xor(pd, 4);
    psv[j] = ps; pdv[j] = pd;
  }
  #pragma unroll
  for (int j = 0; j < 4; ++j){
    int row = base + rq*4 + j;
    if (row < N_NODES){
      uint2 pk;
      pk.x = pack_bf16(acc[j].x, acc[j].y);
      pk.y = pack_bf16(acc[j].z, acc[j].w);
      *(uint2*)(h2b + (size_t)row*16 + 2*cg) = pk;
      if (cg == 0){ asrc[row] = psv[j]; adst[row] = pdv[j]; }
    }
  }
}

// ---------------- conv2: wave/node; 8 edges/iter, bf16 row gathers, LDS-staged e -------
__global__ __launch_bounds__(256) void k_conv2(const unsigned* __restrict__ off,
    const int* __restrict__ csr_src, const unsigned* __restrict__ h2b,
    const float* __restrict__ asrc, const float* __restrict__ adst,
    const float* __restrict__ b2, float* __restrict__ hout)
{
  __shared__ float el[4][72];
  __shared__ int   il[4][72];
  int w    = threadIdx.x >> 6;
  int lane = threadIdx.x & 63;
  int n = blockIdx.x*4 + w;
  if (n >= N_NODES) return;
  unsigned s0 = off[n];
  int deg = (int)(off[n+1] - s0);
  float ad = adst[n];
  int cl = lane & 7;              // feature group: floats 4*cl..4*cl+3
  float4 acc = make_float4(0,0,0,0);
  float den = 0.f;

  if (deg <= 64){
    int idx = 0;
    float a = -1e30f;
    if (lane < deg){
      idx = csr_src[s0 + lane];
      a = leaky02(asrc[idx] + ad);
    }
    float m = a;
    #pragma unroll
    for (int mm = 32; mm >= 1; mm >>= 1) m = fmaxf(m, __shfl_xor(m, mm));
    float e = (lane < deg) ? __expf(a - m) : 0.f;
    el[w][lane] = e;
    il[w][lane] = idx;
    if (lane < 8){ el[w][64+lane] = 0.f; il[w][64+lane] = 0; }
    __builtin_amdgcn_wave_barrier();
    int g8 = lane >> 3;
    #pragma unroll 2
    for (int i = 0; i < deg; i += 8){
      int ii = i + g8;
      float es = el[w][ii];
      int s = il[w][ii];
      uint2 hb = *(const uint2*)(h2b + (size_t)s*16 + 2*cl);
      acc.x += es*bf_lo(hb.x); acc.y += es*bf_hi(hb.x);
      acc.z += es*bf_lo(hb.y); acc.w += es*bf_hi(hb.y);
      den += es;
    }
    #pragma unroll
    for (int mm = 8; mm <= 32; mm <<= 1){
      acc.x += __shfl_xor(acc.x, mm); acc.y += __shfl_xor(acc.y, mm);
      acc.z += __shfl_xor(acc.z, mm); acc.w += __shfl_xor(acc.w, mm);
      den   += __shfl_xor(den, mm);
    }
  } else {
    float m = -1e30f;
    for (int i = lane; i < deg; i += 64){
      int s = csr_src[s0 + i];
      m = fmaxf(m, leaky02(asrc[s] + ad));
    }
    #pragma unroll
    for (int mm = 32; mm >= 1; mm >>= 1) m = fmaxf(m, __shfl_xor(m, mm));
    for (int i = 0; i < deg; ++i){
      int s = csr_src[s0 + i];
      float a = leaky02(asrc[s] + ad);
      float ev = __expf(a - m);
      uint2 hb = *(const uint2*)(h2b + (size_t)s*16 + 2*cl);
      acc.x += ev*bf_lo(hb.x); acc.y += ev*bf_hi(hb.x);
      acc.z += ev*bf_lo(hb.y); acc.w += ev*bf_hi(hb.y);
      den += ev;
    }
  }
  if (lane < 8){
    float inv = 1.f/(den + 1e-16f);
    float4 bv = ((const float4*)b2)[cl];
    float4 o;
    o.x = acc.x*inv + bv.x; o.y = acc.y*inv + bv.y;
    o.z = acc.z*inv + bv.z; o.w = acc.w*inv + bv.w;
    *(float4*)(hout + (size_t)n*32 + 4*cl) = o;
  }
}

// ---------------- pool: one block per graph, contiguous segmented mean -----------------
__global__ __launch_bounds__(256) void k_pool(const int* __restrict__ batch,
    const float* __restrict__ hout, float* __restrict__ gmean)
{
  int g = blockIdx.x;
  int a = 0, b = N_NODES;
  while (a < b){ int mid = (a+b)>>1; if (batch[mid] < g) a = mid+1; else b = mid; }
  int lo = a;
  b = N_NODES;
  while (a < b){ int mid = (a+b)>>1; if (batch[mid] < g+1) a = mid+1; else b = mid; }
  int hi = a;
  int c = threadIdx.x & 31, rg = threadIdx.x >> 5;   // 8 row groups
  float s = 0.f;
  for (int r = lo + rg; r < hi; r += 8) s += hout[(size_t)r*32 + c];
  __shared__ float red[8][32];
  red[rg][c] = s;
  __syncthreads();
  if (rg == 0){
    float t = 0.f;
    #pragma unroll
    for (int k = 0; k < 8; ++k) t += red[k][c];
    gmean[g*32 + c] = t / fmaxf((float)(hi - lo), 1.0f);
  }
}

// ---------------- final MLP (64 graphs, 1 block) ---------------------------------------
__global__ void k_final(const float* __restrict__ gmean,
    const float* __restrict__ l1w, const float* __restrict__ l1b,
    const float* __restrict__ l2w, const float* __restrict__ l2b, float* __restrict__ out)
{
  int t = threadIdx.x;
  if (t >= NG) return;
  float g[32];
  #pragma unroll
  for (int j = 0; j < 32; ++j) g[j] = gmean[t*32 + j];
  float o = l2b[0];
  #pragma unroll
  for (int k = 0; k < 16; ++k){
    float hv = l1b[k];
    #pragma unroll
    for (int j = 0; j < 32; ++j) hv += g[j]*l1w[j*16 + k];
    o += eluf(hv) * l2w[k];
  }
  out[t] = o;
}

extern "C" void kernel_launch(void* const* d_in, const int* in_sizes, int n_in,
                              void* d_out, int out_size, void* d_ws, size_t ws_size,
                              hipStream_t stream) {
  const float* x     = (const float*)d_in[0];
  const int*   ei    = (const int*)  d_in[1];
  const int*   batch = (const int*)  d_in[2];
  const float* W1    = (const float*)d_in[3];
  const float* attS1 = (const float*)d_in[4];
  const float* attD1 = (const float*)d_in[5];
  const float* b1    = (const float*)d_in[6];
  const float* W2    = (const float*)d_in[7];
  const float* attS2 = (const float*)d_in[8];
  const float* attD2 = (const float*)d_in[9];
  const float* b2    = (const float*)d_in[10];
  const float* l1w   = (const float*)d_in[11];
  const float* l1b   = (const float*)d_in[12];
  const float* l2w   = (const float*)d_in[13];
  const float* l2b   = (const float*)d_in[14];
  float* out = (float*)d_out;

  char* w = (char*)d_ws;
  auto alloc = [&](size_t elems) -> void* {
    void* p = (void*)w;
    w += ((elems*4 + 255)/256)*256;
    return p;
  };
  unsigned* csr_off = (unsigned*)alloc(N_NODES + 1);
  unsigned* csr_wp  = (unsigned*)alloc(N_NODES);
  unsigned* deg     = (unsigned*)alloc(N_NODES);
  unsigned* bsum    = (unsigned*)alloc(SCAN_NB);
  unsigned* boff    = (unsigned*)alloc(SCAN_NB);
  int*      csr_src = (int*)     alloc(ETOT);
  unsigned* h1b   = (unsigned*)alloc((size_t)N_NODES*64);   // bf16-packed [N,128]
  float*    asrc1 = (float*)alloc((size_t)N_NODES*4);
  float*    adst1 = (float*)alloc((size_t)N_NODES*4);
  float*    helu  = (float*)alloc((size_t)N_NODES*128);
  unsigned* h2b   = (unsigned*)alloc((size_t)N_NODES*16);   // bf16-packed [N,32]
  float*    asrc2 = (float*)alloc(N_NODES);
  float*    adst2 = (float*)alloc(N_NODES);
  float*    hout  = (float*)alloc((size_t)N_NODES*32);
  float*    gmean = (float*)alloc(NG*32);

  k_init_deg<<<SCAN_NB, 256, 0, stream>>>(deg);
  k_count   <<<(N_EDGES + 255)/256, 256, 0, stream>>>(ei, deg);
  k_scan1   <<<SCAN_NB, 256, 0, stream>>>(deg, bsum);
  k_scan2   <<<1, 256, 0, stream>>>(bsum, boff);
  k_scan3   <<<SCAN_NB, 256, 0, stream>>>(deg, boff, csr_off, csr_wp);
  k_scatter <<<(ETOT + 255)/256, 256, 0, stream>>>(ei, csr_wp, csr_src);

  k_gemm1<<<(N_NODES + 127)/128, 256, 0, stream>>>(x, W1, attS1, attD1, h1b, asrc1, adst1);
  k_conv1<<<(N_NODES + 3)/4, 256, 0, stream>>>(csr_off, csr_src, h1b, asrc1, adst1, b1, helu);
  k_gemm2<<<(N_NODES + 127)/128, 256, 0, stream>>>(helu, W2, attS2, attD2, h2b, asrc2, adst2);
  k_conv2<<<(N_NODES + 3)/4, 256, 0, stream>>>(csr_off, csr_src, h2b, asrc2, adst2, b2, hout);
  k_pool <<<NG, 256, 0, stream>>>(batch, hout, gmean);
  k_final<<<1, 64, 0, stream>>>(gmean, l1w, l1b, l2w, l2b, out);
}

// Round 7
// 188.428 us; speedup vs baseline: 4.5390x; 1.3456x over previous
//
#include <hip/hip_runtime.h>
#include <math.h>

#define N_NODES 50000
#define N_EDGES 800000
#define ETOT (N_EDGES + N_NODES)
#define NG 64
#define NBUCK 196                 // dst buckets of 256 nodes
#define CHUNK 4096
#define NCHUNK ((ETOT + CHUNK - 1)/CHUNK)   // 208
#define SCANN (NBUCK*NCHUNK)      // 40768
#define GSB ((SCANN + 255)/256)   // 160

__device__ __forceinline__ float leaky02(float a){ return a > 0.f ? a : 0.2f*a; }
__device__ __forceinline__ float eluf(float v){ return v > 0.f ? v : expm1f(v); }

// round-to-nearest-even f32->bf16, packed pair (a low, b high)
__device__ __forceinline__ unsigned pack_bf16(float a, float b){
  unsigned ua = __float_as_uint(a); ua += 0x7fffu + ((ua >> 16) & 1u);
  unsigned ub = __float_as_uint(b); ub += 0x7fffu + ((ub >> 16) & 1u);
  return (ua >> 16) | (ub & 0xffff0000u);
}
__device__ __forceinline__ float bf_lo(unsigned v){ return __uint_as_float(v << 16); }
__device__ __forceinline__ float bf_hi(unsigned v){ return __uint_as_float(v & 0xffff0000u); }

// ---------------- bucketed CSR build (by dst) ------------------------------------------
// edges = [E real] + [N self-loops]; bucket = dst>>8 (196 buckets x 256 nodes)

__global__ __launch_bounds__(256) void k_hist(const int* __restrict__ ei,
                                              unsigned* __restrict__ cnt){
  __shared__ unsigned hist[NBUCK];
  int tid = threadIdx.x;
  for (int t = tid; t < NBUCK; t += 256) hist[t] = 0;
  __syncthreads();
  int base = blockIdx.x * CHUNK;
  #pragma unroll
  for (int i = 0; i < CHUNK/256; ++i){
    int e = base + i*256 + tid;
    if (e < ETOT){
      int d = (e < N_EDGES) ? ei[N_EDGES + e] : (e - N_EDGES);
      atomicAdd(&hist[d >> 8], 1u);
    }
  }
  __syncthreads();
  for (int t = tid; t < NBUCK; t += 256) cnt[t*NCHUNK + blockIdx.x] = hist[t];
}

// generic 3-kernel exclusive scan (n <= 256*256)
__global__ __launch_bounds__(256) void g_scan1(const unsigned* __restrict__ in,
    unsigned* __restrict__ bsum, int n){
  int i = blockIdx.x*256 + threadIdx.x;
  unsigned v = (i < n) ? in[i] : 0u;
  #pragma unroll
  for (int o = 32; o >= 1; o >>= 1) v += __shfl_xor(v, o);
  __shared__ unsigned ws[4];
  if ((threadIdx.x & 63) == 0) ws[threadIdx.x >> 6] = v;
  __syncthreads();
  if (threadIdx.x == 0) bsum[blockIdx.x] = ws[0] + ws[1] + ws[2] + ws[3];
}

__global__ __launch_bounds__(256) void g_scan2(const unsigned* __restrict__ bsum,
    unsigned* __restrict__ boff, int nb){
  __shared__ unsigned ts[256];
  int t = threadIdx.x;
  unsigned v = (t < nb) ? bsum[t] : 0u;
  ts[t] = v; __syncthreads();
  for (int o = 1; o < 256; o <<= 1){
    unsigned u = (t >= o) ? ts[t-o] : 0u;
    __syncthreads();
    ts[t] += u;
    __syncthreads();
  }
  if (t < nb) boff[t] = ts[t] - v;
}

__global__ __launch_bounds__(256) void g_scan3(const unsigned* __restrict__ in,
    const unsigned* __restrict__ boff, unsigned* __restrict__ out, int n){
  __shared__ unsigned ts[256];
  int t = threadIdx.x, i = blockIdx.x*256 + t;
  unsigned v = (i < n) ? in[i] : 0u;
  ts[t] = v; __syncthreads();
  for (int o = 1; o < 256; o <<= 1){
    unsigned u = (t >= o) ? ts[t-o] : 0u;
    __syncthreads();
    ts[t] += u;
    __syncthreads();
  }
  if (i < n) out[i] = boff[blockIdx.x] + ts[t] - v;
}

// partition edges into bucket-contiguous staging, packed src|dst_local<<16 (N < 2^16)
__global__ __launch_bounds__(256) void k_part(const int* __restrict__ ei,
    const unsigned* __restrict__ basev, unsigned* __restrict__ staging){
  __shared__ unsigned cur[NBUCK];
  int tid = threadIdx.x;
  for (int t = tid; t < NBUCK; t += 256) cur[t] = basev[t*NCHUNK + blockIdx.x];
  __syncthreads();
  int base = blockIdx.x * CHUNK;
  #pragma unroll
  for (int i = 0; i < CHUNK/256; ++i){
    int e = base + i*256 + tid;
    if (e < ETOT){
      int s, d;
      if (e < N_EDGES){ s = ei[e]; d = ei[N_EDGES + e]; } else { s = d = e - N_EDGES; }
      unsigned pos = atomicAdd(&cur[d >> 8], 1u);
      staging[pos] = (unsigned)s | ((unsigned)(d & 255) << 16);
    }
  }
}

// per-bucket CSR finalize: LDS count + scan -> csr_off (coalesced) + hot-window scatter
__global__ __launch_bounds__(256) void k_csr(const unsigned* __restrict__ basev,
    const unsigned* __restrict__ staging, unsigned* __restrict__ off,
    int* __restrict__ csr_src){
  __shared__ unsigned ts[256], cur[256];
  int tid = threadIdx.x, b = blockIdx.x;
  unsigned start = basev[b*NCHUNK];
  unsigned end = (b == NBUCK-1) ? (unsigned)ETOT : basev[(b+1)*NCHUNK];
  ts[tid] = 0;
  __syncthreads();
  for (unsigned i = start + tid; i < end; i += 256)
    atomicAdd(&ts[staging[i] >> 16], 1u);
  __syncthreads();
  unsigned v = ts[tid];
  for (int o = 1; o < 256; o <<= 1){
    unsigned u = (tid >= o) ? ts[tid-o] : 0u;
    __syncthreads();
    ts[tid] += u;
    __syncthreads();
  }
  unsigned excl = ts[tid] - v;
  int node = (b << 8) + tid;
  if (node < N_NODES) off[node] = start + excl;
  if (b == 0 && tid == 0) off[N_NODES] = (unsigned)ETOT;
  cur[tid] = excl;
  __syncthreads();
  for (unsigned i = start + tid; i < end; i += 256){
    unsigned p = staging[i];
    unsigned pos = atomicAdd(&cur[p >> 16], 1u);
    csr_src[start + pos] = (int)(p & 0xffffu);
  }
}

// ---------------- GEMM1: h1 = x @ W1 (128x128), h1 stored bf16-packed ------------------
__global__ __launch_bounds__(256) void k_gemm1(const float* __restrict__ x,
    const float* __restrict__ W, const float* __restrict__ attS, const float* __restrict__ attD,
    unsigned* __restrict__ h1b, float* __restrict__ asrc, float* __restrict__ adst)
{
  __shared__ float ws[64*128];    // 32 KB
  __shared__ float xs[128*68];    // 34.8 KB
  int tid = threadIdx.x;
  int base = blockIdx.x * 128;
  int cg = tid & 15, rq = tid >> 4;        // 16 col-groups x 16 row-groups
  float4 acc[8][2];
  #pragma unroll
  for (int j = 0; j < 8; ++j){ acc[j][0] = make_float4(0,0,0,0); acc[j][1] = make_float4(0,0,0,0); }

  for (int p = 0; p < 2; ++p){
    if (p) __syncthreads();
    #pragma unroll
    for (int i = 0; i < 8; ++i){         // stage W[64k x 128c], swizzled slots
      int l = tid + i*256;
      int k = l >> 5, c4 = l & 31;
      float4 v = *(const float4*)(W + (size_t)(p*64 + k)*128 + 4*c4);
      int phys = (c4 >> 1) | ((c4 & 1) << 4);
      *(float4*)(ws + k*128 + 4*phys) = v;
    }
    #pragma unroll
    for (int i = 0; i < 8; ++i){         // stage x[128r x 64k]
      int l = tid + i*256;
      int r = l >> 4, c4 = l & 15;
      float4 v = make_float4(0,0,0,0);
      if (base + r < N_NODES) v = *(const float4*)(x + (size_t)(base+r)*128 + p*64 + 4*c4);
      *(float4*)(xs + r*68 + 4*c4) = v;
    }
    __syncthreads();
    #pragma unroll 1
    for (int kk = 0; kk < 16; ++kk){
      float4 xv[8], wv[4][2];
      #pragma unroll
      for (int j = 0; j < 8; ++j) xv[j] = *(const float4*)(xs + (rq*8 + j)*68 + 4*kk);
      #pragma unroll
      for (int t = 0; t < 4; ++t){
        wv[t][0] = *(const float4*)(ws + (4*kk + t)*128 + 4*cg);
        wv[t][1] = *(const float4*)(ws + (4*kk + t)*128 + 4*(cg + 16));
      }
      #pragma unroll
      for (int j = 0; j < 8; ++j){
        #pragma unroll
        for (int t = 0; t < 4; ++t){
          float xf = (t==0) ? xv[j].x : (t==1) ? xv[j].y : (t==2) ? xv[j].z : xv[j].w;
          #pragma unroll
          for (int u = 0; u < 2; ++u){
            acc[j][u].x += xf*wv[t][u].x; acc[j][u].y += xf*wv[t][u].y;
            acc[j][u].z += xf*wv[t][u].z; acc[j][u].w += xf*wv[t][u].w;
          }
        }
      }
    }
  }
  // epilogue: bf16 h1 + per-head alphas (f32)
  int hd = cg >> 2, lc = 8*(cg & 3);
  float s0v[8], s1v[8];
  #pragma unroll
  for (int j = 0; j < 8; ++j){
    float ps = 0.f, pd = 0.f;
    #pragma unroll
    for (int u = 0; u < 2; ++u){
      const float* aS = attS + hd*32 + lc + 4*u;
      const float* aD = attD + hd*32 + lc + 4*u;
      ps += acc[j][u].x*aS[0] + acc[j][u].y*aS[1] + acc[j][u].z*aS[2] + acc[j][u].w*aS[3];
      pd += acc[j][u].x*aD[0] + acc[j][u].y*aD[1] + acc[j][u].z*aD[2] + acc[j][u].w*aD[3];
    }
    ps += __shfl_xor(ps, 1); ps += __shfl_xor(ps, 2);
    pd += __shfl_xor(pd, 1); pd += __shfl_xor(pd, 2);
    s0v[j] = ps; s1v[j] = pd;
  }
  #pragma unroll
  for (int j = 0; j < 8; ++j){
    int row = base + rq*8 + j;
    if (row < N_NODES){
      uint4 pk;
      pk.x = pack_bf16(acc[j][0].x, acc[j][0].y);
      pk.y = pack_bf16(acc[j][0].z, acc[j][0].w);
      pk.z = pack_bf16(acc[j][1].x, acc[j][1].y);
      pk.w = pack_bf16(acc[j][1].z, acc[j][1].w);
      *(uint4*)(h1b + (size_t)row*64 + 4*cg) = pk;
      if ((cg & 3) == 0){ asrc[row*4 + hd] = s0v[j]; adst[row*4 + hd] = s1v[j]; }
    }
  }
}

// ---------------- conv1: wave/node; 2 edges/iter, bf16 row gathers, LDS-staged e -------
__global__ __launch_bounds__(256) void k_conv1(const unsigned* __restrict__ off,
    const int* __restrict__ csr_src, const unsigned* __restrict__ h1b,
    const float* __restrict__ asrc, const float* __restrict__ adst,
    const float* __restrict__ b1, float* __restrict__ helu)
{
  __shared__ float4 eh4[4][68];   // [wave][edge] -> e for heads 0..3
  __shared__ int    idxs[4][68];
  int w    = threadIdx.x >> 6;
  int lane = threadIdx.x & 63;
  int n = blockIdx.x*4 + w;
  if (n >= N_NODES) return;
  unsigned s0 = off[n];
  int deg = (int)(off[n+1] - s0);
  float4 ad = *(const float4*)(adst + (size_t)n*4);
  int cl = lane & 31;             // feature group: floats 4*cl..4*cl+3
  int h  = cl >> 3;               // head of this feature group
  float4 acc = make_float4(0,0,0,0);
  float den = 0.f;

  if (deg <= 64){
    int idx = 0;
    float a0=-1e30f, a1=-1e30f, a2=-1e30f, a3=-1e30f;
    if (lane < deg){
      idx = csr_src[s0 + lane];
      float4 as = *(const float4*)(asrc + (size_t)idx*4);
      a0 = leaky02(as.x + ad.x); a1 = leaky02(as.y + ad.y);
      a2 = leaky02(as.z + ad.z); a3 = leaky02(as.w + ad.w);
    }
    float m0=a0, m1=a1, m2=a2, m3=a3;
    #pragma unroll
    for (int m = 32; m >= 1; m >>= 1){
      m0 = fmaxf(m0, __shfl_xor(m0, m)); m1 = fmaxf(m1, __shfl_xor(m1, m));
      m2 = fmaxf(m2, __shfl_xor(m2, m)); m3 = fmaxf(m3, __shfl_xor(m3, m));
    }
    float4 ev = make_float4(0,0,0,0);
    if (lane < deg){
      ev.x = __expf(a0-m0); ev.y = __expf(a1-m1);
      ev.z = __expf(a2-m2); ev.w = __expf(a3-m3);
    }
    eh4[w][lane] = ev;
    idxs[w][lane] = idx;
    if (lane < 4){ eh4[w][64+lane] = make_float4(0,0,0,0); idxs[w][64+lane] = 0; }
    __builtin_amdgcn_wave_barrier();   // wave-coherent LDS: in-order DS, no s_barrier
    int half = lane >> 5;
    #pragma unroll 4
    for (int i = 0; i < deg; i += 2){
      int ii = i + half;
      float es = ((const float*)&eh4[w][ii])[h];
      int s = idxs[w][ii];
      uint2 hb = *(const uint2*)(h1b + (size_t)s*64 + 2*cl);
      acc.x += es*bf_lo(hb.x); acc.y += es*bf_hi(hb.x);
      acc.z += es*bf_lo(hb.y); acc.w += es*bf_hi(hb.y);
      den += es;
    }
    acc.x += __shfl_xor(acc.x, 32); acc.y += __shfl_xor(acc.y, 32);
    acc.z += __shfl_xor(acc.z, 32); acc.w += __shfl_xor(acc.w, 32);
    den   += __shfl_xor(den, 32);
  } else {
    float m0=-1e30f, m1=-1e30f, m2=-1e30f, m3=-1e30f;
    for (int i = lane; i < deg; i += 64){
      int s = csr_src[s0 + i];
      float4 as = *(const float4*)(asrc + (size_t)s*4);
      m0 = fmaxf(m0, leaky02(as.x + ad.x)); m1 = fmaxf(m1, leaky02(as.y + ad.y));
      m2 = fmaxf(m2, leaky02(as.z + ad.z)); m3 = fmaxf(m3, leaky02(as.w + ad.w));
    }
    #pragma unroll
    for (int m = 32; m >= 1; m >>= 1){
      m0 = fmaxf(m0, __shfl_xor(m0, m)); m1 = fmaxf(m1, __shfl_xor(m1, m));
      m2 = fmaxf(m2, __shfl_xor(m2, m)); m3 = fmaxf(m3, __shfl_xor(m3, m));
    }
    float mh  = (h==0) ? m0 : (h==1) ? m1 : (h==2) ? m2 : m3;
    float adh = (h==0) ? ad.x : (h==1) ? ad.y : (h==2) ? ad.z : ad.w;
    for (int i = 0; i < deg; ++i){
      int s = csr_src[s0 + i];
      float a = leaky02(asrc[s*4 + h] + adh);
      float ev = __expf(a - mh);
      uint2 hb = *(const uint2*)(h1b + (size_t)s*64 + 2*cl);
      acc.x += ev*bf_lo(hb.x); acc.y += ev*bf_hi(hb.x);
      acc.z += ev*bf_lo(hb.y); acc.w += ev*bf_hi(hb.y);
      den += ev;
    }
  }
  if (lane < 32){
    float inv = 1.f/(den + 1e-16f);
    float4 bv = ((const float4*)b1)[cl];
    float4 o;
    o.x = eluf(acc.x*inv + bv.x); o.y = eluf(acc.y*inv + bv.y);
    o.z = eluf(acc.z*inv + bv.z); o.w = eluf(acc.w*inv + bv.w);
    *(float4*)(helu + (size_t)n*128 + 4*cl) = o;
  }
}

// ---------------- GEMM2: h2 = helu @ W2 (128x32), h2 stored bf16-packed ----------------
__global__ __launch_bounds__(256) void k_gemm2(const float* __restrict__ xin,
    const float* __restrict__ W, const float* __restrict__ attS, const float* __restrict__ attD,
    unsigned* __restrict__ h2b, float* __restrict__ asrc, float* __restrict__ adst)
{
  __shared__ float ws[64*32];     // 8 KB
  __shared__ float xs[128*68];    // 34.8 KB
  int tid = threadIdx.x;
  int base = blockIdx.x * 128;
  int cg = tid & 7, rq = tid >> 3;         // 8 col-groups x 32 row-groups
  float4 acc[4];
  #pragma unroll
  for (int j = 0; j < 4; ++j) acc[j] = make_float4(0,0,0,0);

  for (int p = 0; p < 2; ++p){
    if (p) __syncthreads();
    #pragma unroll
    for (int i = 0; i < 2; ++i){         // stage W2[64k x 32c]
      int l = tid + i*256;
      int k = l >> 3, c4 = l & 7;
      *(float4*)(ws + k*32 + 4*c4) = *(const float4*)(W + (size_t)(p*64 + k)*32 + 4*c4);
    }
    #pragma unroll
    for (int i = 0; i < 8; ++i){         // stage xin[128r x 64k]
      int l = tid + i*256;
      int r = l >> 4, c4 = l & 15;
      float4 v = make_float4(0,0,0,0);
      if (base + r < N_NODES) v = *(const float4*)(xin + (size_t)(base+r)*128 + p*64 + 4*c4);
      *(float4*)(xs + r*68 + 4*c4) = v;
    }
    __syncthreads();
    #pragma unroll 1
    for (int kk = 0; kk < 16; ++kk){
      float4 xv[4], wv[4];
      #pragma unroll
      for (int j = 0; j < 4; ++j) xv[j] = *(const float4*)(xs + (rq*4 + j)*68 + 4*kk);
      #pragma unroll
      for (int t = 0; t < 4; ++t) wv[t] = *(const float4*)(ws + (4*kk + t)*32 + 4*cg);
      #pragma unroll
      for (int j = 0; j < 4; ++j){
        #pragma unroll
        for (int t = 0; t < 4; ++t){
          float xf = (t==0) ? xv[j].x : (t==1) ? xv[j].y : (t==2) ? xv[j].z : xv[j].w;
          acc[j].x += xf*wv[t].x; acc[j].y += xf*wv[t].y;
          acc[j].z += xf*wv[t].z; acc[j].w += xf*wv[t].w;
        }
      }
    }
  }
  // epilogue
  float psv[4], pdv[4];
  #pragma unroll
  for (int j = 0; j < 4; ++j){
    const float* aS = attS + 4*cg;
    const float* aD = attD + 4*cg;
    float ps = acc[j].x*aS[0] + acc[j].y*aS[1] + acc[j].z*aS[2] + acc[j].w*aS[3];
    float pd = acc[j].x*aD[0] + acc[j].y*aD[1] + acc[j].z*aD[2] + acc[j].w*aD[3];
    ps += __shfl_xor(ps, 1); ps += __shfl_xor(ps, 2); ps += __shfl_xor(ps, 4);
    pd += __shfl_xor(pd, 1); pd += __shfl_xor(pd, 2); pd += __shfl_xor(pd, 4);
    psv[j] = ps; pdv[j] = pd;
  }
  #pragma unroll
  for (int j = 0; j < 4; ++j){
    int row = base + rq*4 + j;
    if (row < N_NODES){
      uint2 pk;
      pk.x = pack_bf16(acc[j].x, acc[j].y);
      pk.y = pack_bf16(acc[j].z, acc[j].w);
      *(uint2*)(h2b + (size_t)row*16 + 2*cg) = pk;
      if (cg == 0){ asrc[row] = psv[j]; adst[row] = pdv[j]; }
    }
  }
}

// ---------------- conv2: wave/node; 8 edges/iter, bf16 row gathers, LDS-staged e -------
__global__ __launch_bounds__(256) void k_conv2(const unsigned* __restrict__ off,
    const int* __restrict__ csr_src, const unsigned* __restrict__ h2b,
    const float* __restrict__ asrc, const float* __restrict__ adst,
    const float* __restrict__ b2, float* __restrict__ hout)
{
  __shared__ float el[4][72];
  __shared__ int   il[4][72];
  int w    = threadIdx.x >> 6;
  int lane = threadIdx.x & 63;
  int n = blockIdx.x*4 + w;
  if (n >= N_NODES) return;
  unsigned s0 = off[n];
  int deg = (int)(off[n+1] - s0);
  float ad = adst[n];
  int cl = lane & 7;              // feature group: floats 4*cl..4*cl+3
  float4 acc = make_float4(0,0,0,0);
  float den = 0.f;

  if (deg <= 64){
    int idx = 0;
    float a = -1e30f;
    if (lane < deg){
      idx = csr_src[s0 + lane];
      a = leaky02(asrc[idx] + ad);
    }
    float m = a;
    #pragma unroll
    for (int mm = 32; mm >= 1; mm >>= 1) m = fmaxf(m, __shfl_xor(m, mm));
    float e = (lane < deg) ? __expf(a - m) : 0.f;
    el[w][lane] = e;
    il[w][lane] = idx;
    if (lane < 8){ el[w][64+lane] = 0.f; il[w][64+lane] = 0; }
    __builtin_amdgcn_wave_barrier();
    int g8 = lane >> 3;
    #pragma unroll 2
    for (int i = 0; i < deg; i += 8){
      int ii = i + g8;
      float es = el[w][ii];
      int s = il[w][ii];
      uint2 hb = *(const uint2*)(h2b + (size_t)s*16 + 2*cl);
      acc.x += es*bf_lo(hb.x); acc.y += es*bf_hi(hb.x);
      acc.z += es*bf_lo(hb.y); acc.w += es*bf_hi(hb.y);
      den += es;
    }
    #pragma unroll
    for (int mm = 8; mm <= 32; mm <<= 1){
      acc.x += __shfl_xor(acc.x, mm); acc.y += __shfl_xor(acc.y, mm);
      acc.z += __shfl_xor(acc.z, mm); acc.w += __shfl_xor(acc.w, mm);
      den   += __shfl_xor(den, mm);
    }
  } else {
    float m = -1e30f;
    for (int i = lane; i < deg; i += 64){
      int s = csr_src[s0 + i];
      m = fmaxf(m, leaky02(asrc[s] + ad));
    }
    #pragma unroll
    for (int mm = 32; mm >= 1; mm >>= 1) m = fmaxf(m, __shfl_xor(m, mm));
    for (int i = 0; i < deg; ++i){
      int s = csr_src[s0 + i];
      float a = leaky02(asrc[s] + ad);
      float ev = __expf(a - m);
      uint2 hb = *(const uint2*)(h2b + (size_t)s*16 + 2*cl);
      acc.x += ev*bf_lo(hb.x); acc.y += ev*bf_hi(hb.x);
      acc.z += ev*bf_lo(hb.y); acc.w += ev*bf_hi(hb.y);
      den += ev;
    }
  }
  if (lane < 8){
    float inv = 1.f/(den + 1e-16f);
    float4 bv = ((const float4*)b2)[cl];
    float4 o;
    o.x = acc.x*inv + bv.x; o.y = acc.y*inv + bv.y;
    o.z = acc.z*inv + bv.z; o.w = acc.w*inv + bv.w;
    *(float4*)(hout + (size_t)n*32 + 4*cl) = o;
  }
}

// ---------------- pool: one block per graph, contiguous segmented mean -----------------
__global__ __launch_bounds__(256) void k_pool(const int* __restrict__ batch,
    const float* __restrict__ hout, float* __restrict__ gmean)
{
  int g = blockIdx.x;
  int a = 0, b = N_NODES;
  while (a < b){ int mid = (a+b)>>1; if (batch[mid] < g) a = mid+1; else b = mid; }
  int lo = a;
  b = N_NODES;
  while (a < b){ int mid = (a+b)>>1; if (batch[mid] < g+1) a = mid+1; else b = mid; }
  int hi = a;
  int c = threadIdx.x & 31, rg = threadIdx.x >> 5;   // 8 row groups
  float s = 0.f;
  for (int r = lo + rg; r < hi; r += 8) s += hout[(size_t)r*32 + c];
  __shared__ float red[8][32];
  red[rg][c] = s;
  __syncthreads();
  if (rg == 0){
    float t = 0.f;
    #pragma unroll
    for (int k = 0; k < 8; ++k) t += red[k][c];
    gmean[g*32 + c] = t / fmaxf((float)(hi - lo), 1.0f);
  }
}

// ---------------- final MLP (64 graphs, 1 block) ---------------------------------------
__global__ void k_final(const float* __restrict__ gmean,
    const float* __restrict__ l1w, const float* __restrict__ l1b,
    const float* __restrict__ l2w, const float* __restrict__ l2b, float* __restrict__ out)
{
  int t = threadIdx.x;
  if (t >= NG) return;
  float g[32];
  #pragma unroll
  for (int j = 0; j < 32; ++j) g[j] = gmean[t*32 + j];
  float o = l2b[0];
  #pragma unroll
  for (int k = 0; k < 16; ++k){
    float hv = l1b[k];
    #pragma unroll
    for (int j = 0; j < 32; ++j) hv += g[j]*l1w[j*16 + k];
    o += eluf(hv) * l2w[k];
  }
  out[t] = o;
}

extern "C" void kernel_launch(void* const* d_in, const int* in_sizes, int n_in,
                              void* d_out, int out_size, void* d_ws, size_t ws_size,
                              hipStream_t stream) {
  const float* x     = (const float*)d_in[0];
  const int*   ei    = (const int*)  d_in[1];
  const int*   batch = (const int*)  d_in[2];
  const float* W1    = (const float*)d_in[3];
  const float* attS1 = (const float*)d_in[4];
  const float* attD1 = (const float*)d_in[5];
  const float* b1    = (const float*)d_in[6];
  const float* W2    = (const float*)d_in[7];
  const float* attS2 = (const float*)d_in[8];
  const float* attD2 = (const float*)d_in[9];
  const float* b2    = (const float*)d_in[10];
  const float* l1w   = (const float*)d_in[11];
  const float* l1b   = (const float*)d_in[12];
  const float* l2w   = (const float*)d_in[13];
  const float* l2b   = (const float*)d_in[14];
  float* out = (float*)d_out;

  char* w = (char*)d_ws;
  auto alloc = [&](size_t elems) -> void* {
    void* p = (void*)w;
    w += ((elems*4 + 255)/256)*256;
    return p;
  };
  unsigned* csr_off = (unsigned*)alloc(N_NODES + 1);
  unsigned* cnt     = (unsigned*)alloc(SCANN);
  unsigned* basev   = (unsigned*)alloc(SCANN);
  unsigned* gbs     = (unsigned*)alloc(GSB);
  unsigned* gbo     = (unsigned*)alloc(GSB);
  unsigned* staging = (unsigned*)alloc(ETOT);
  int*      csr_src = (int*)     alloc(ETOT);
  unsigned* h1b   = (unsigned*)alloc((size_t)N_NODES*64);   // bf16-packed [N,128]
  float*    asrc1 = (float*)alloc((size_t)N_NODES*4);
  float*    adst1 = (float*)alloc((size_t)N_NODES*4);
  float*    helu  = (float*)alloc((size_t)N_NODES*128);
  unsigned* h2b   = (unsigned*)alloc((size_t)N_NODES*16);   // bf16-packed [N,32]
  float*    asrc2 = (float*)alloc(N_NODES);
  float*    adst2 = (float*)alloc(N_NODES);
  float*    hout  = (float*)alloc((size_t)N_NODES*32);
  float*    gmean = (float*)alloc(NG*32);

  k_hist <<<NCHUNK, 256, 0, stream>>>(ei, cnt);
  g_scan1<<<GSB, 256, 0, stream>>>(cnt, gbs, SCANN);
  g_scan2<<<1, 256, 0, stream>>>(gbs, gbo, GSB);
  g_scan3<<<GSB, 256, 0, stream>>>(cnt, gbo, basev, SCANN);
  k_part <<<NCHUNK, 256, 0, stream>>>(ei, basev, staging);
  k_csr  <<<NBUCK, 256, 0, stream>>>(basev, staging, csr_off, csr_src);

  k_gemm1<<<(N_NODES + 127)/128, 256, 0, stream>>>(x, W1, attS1, attD1, h1b, asrc1, adst1);
  k_conv1<<<(N_NODES + 3)/4, 256, 0, stream>>>(csr_off, csr_src, h1b, asrc1, adst1, b1, helu);
  k_gemm2<<<(N_NODES + 127)/128, 256, 0, stream>>>(helu, W2, attS2, attD2, h2b, asrc2, adst2);
  k_conv2<<<(N_NODES + 3)/4, 256, 0, stream>>>(csr_off, csr_src, h2b, asrc2, adst2, b2, hout);
  k_pool <<<NG, 256, 0, stream>>>(batch, hout, gmean);
  k_final<<<1, 64, 0, stream>>>(gmean, l1w, l1b, l2w, l2b, out);
}